// Round 9
// baseline (756.121 us; speedup 1.0000x reference)
//
#include <hip/hip_runtime.h>
#include <hip/hip_bf16.h>
#include <math.h>

#define NG     32
#define NVARS  16384
#define NCLS   32768
#define NLITS  98304
#define NROUNDS 4

typedef __attribute__((ext_vector_type(8))) short bf16x8;
typedef __attribute__((ext_vector_type(4))) float f32x4;

// ---------------- workspace layout (float units) ----------------
#define OFF_VAR    ((size_t)0)            // f32 16384x128
#define OFF_CST    ((size_t)2097152)      // f32 32768x128
#define OFF_XCMB   ((size_t)6291456)      // bf16 32768x192
#define OFF_XUGB   ((size_t)9437184)      // bf16 16384x256
#define OFF_ABUF   ((size_t)11534336)     // (unused)
#define OFF_BBUF   ((size_t)17825792)     // bf16 32768x384 (cm1 out)
#define OFF_CD     ((size_t)24117248)     // bf16 32768x192 (also UO 16384x128 bf16)
#define OFF_Q      ((size_t)30408704)     // f32 16384x32
#define OFF_VLOSS  ((size_t)31981568)     // bf16 32768x32
#define OFF_CMEAN  ((size_t)33030144)     // f32 32x128 (cmean+vmean contiguous)
#define OFF_VMEAN  ((size_t)33034240)     // f32 32x128
#define OFF_LOSS   ((size_t)33038336)     // f32 1
#define OFF_CSO    ((size_t)33038340)     // int 16385
#define OFF_CSE    ((size_t)33054725)     // int 98304 ((clause<<1)|pos)
#define OFF_CSC    ((size_t)33153029)     // int 16384
#define OFF_WT     ((size_t)33169416)     // bf16 pool 507904 elems

#define WT_CM0  ((size_t)0)       // [384][192]
#define WT_CM1  ((size_t)73728)   // [384][384]
#define WT_CM2  ((size_t)221184)  // [192][384]
#define WT_UG0  ((size_t)294912)  // [256][256]
#define WT_UG1  ((size_t)360448)  // [256][256]
#define WT_UG2  ((size_t)425984)  // [128][256]
#define WT_VO0  ((size_t)458752)  // [128][128]
#define WT_VO1  ((size_t)475136)  // [128][128]
#define WT_VQ0  ((size_t)491520)  // [64][160]
#define WT_VQ1  ((size_t)501760)  // [64][64]
#define WT_VQ2  ((size_t)505856)  // [32][64]

__device__ __forceinline__ float softplus_f(float x) {
  return fmaxf(x, 0.f) + log1pf(expf(-fabsf(x)));
}
__device__ __forceinline__ short f2bf(float x) {
  __hip_bfloat16 h = __float2bfloat16(x);
  return *reinterpret_cast<short*>(&h);
}
__device__ __forceinline__ float bf2f(short s) {
  __hip_bfloat16 h = *reinterpret_cast<__hip_bfloat16*>(&s);
  return __bfloat162float(h);
}

// ---------------- init ----------------
__global__ void init_state_kernel(float* __restrict__ var, float* __restrict__ cst,
                                  short* __restrict__ xugb, short* __restrict__ xcmb,
                                  float* __restrict__ loss, int* __restrict__ cnt) {
  int t = blockIdx.x * blockDim.x + threadIdx.x;
  if (t == 0) *loss = 0.f;
  const int main_total = (NVARS + NCLS) * 128;
  if (t < main_total) {
    int row = t >> 7, m = t & 127;
    const float base = 2.82842712474619f; // sqrt(128)*0.25
    float val = ((m == 0) ? (1.f - 1.f / 128.f) : (-1.f / 128.f)) * base;
    if (row < NVARS) {
      var[(size_t)row * 128 + m] = val;
      xugb[(size_t)row * 256 + m] = f2bf(val);
    } else {
      int c = row - NVARS;
      cst[(size_t)c * 128 + m] = val;
      xcmb[(size_t)c * 192 + m] = f2bf(val);
    }
    return;
  }
  int t2 = t - main_total;
  if (t2 < NVARS * 32) {           // xugb cols 224..255 = 0 forever
    int row = t2 >> 5, j = t2 & 31;
    xugb[(size_t)row * 256 + 224 + j] = 0;
    return;
  }
  int t3 = t2 - NVARS * 32;
  if (t3 < NCLS * 32) {            // xcmb cols 160..191 = 0 forever
    int row = t3 >> 5, j = t3 & 31;
    xcmb[(size_t)row * 192 + 160 + j] = 0;
    return;
  }
  int t4 = t3 - NCLS * 32;
  if (t4 < NVARS) cnt[t4] = 0;
}

// ---------------- CSR build ----------------
__global__ void csr_count_kernel(const int* __restrict__ lit_var, int* __restrict__ cnt) {
  int l = blockIdx.x * blockDim.x + threadIdx.x;
  if (l >= NLITS) return;
  atomicAdd(&cnt[lit_var[l]], 1);
}

__global__ __launch_bounds__(1024) void csr_scan_kernel(const int* __restrict__ cnt,
                                                        int* __restrict__ cso,
                                                        int* __restrict__ cur) {
  __shared__ int part[1024];
  int t = threadIdx.x;
  int base = t * 16;
  int local[16];
  int s = 0;
  #pragma unroll
  for (int i = 0; i < 16; ++i) { local[i] = cnt[base + i]; s += local[i]; }
  part[t] = s;
  __syncthreads();
  for (int off = 1; off < 1024; off <<= 1) {
    int v = (t >= off) ? part[t - off] : 0;
    __syncthreads();
    part[t] += v;
    __syncthreads();
  }
  int run = part[t] - s;
  #pragma unroll
  for (int i = 0; i < 16; ++i) {
    cso[base + i] = run;
    cur[base + i] = run;
    run += local[i];
  }
  if (t == 1023) cso[NVARS] = run;
}

__global__ void csr_fill_kernel(const int* __restrict__ lit_var, const int* __restrict__ lit_sign,
                                const int* __restrict__ lit_clause,
                                int* __restrict__ cur, int* __restrict__ cse) {
  int l = blockIdx.x * blockDim.x + threadIdx.x;
  if (l >= NLITS) return;
  int v = lit_var[l];
  int pos = atomicAdd(&cur[v], 1);
  cse[pos] = (lit_clause[l] << 1) | (lit_sign[l] > 0 ? 1 : 0);
}

// ---------------- weight convert ----------------
__global__ void convert_all_kernel(
    const float* __restrict__ cm_w0, const float* __restrict__ cm_w1, const float* __restrict__ cm_w2,
    const float* __restrict__ ug_w0, const float* __restrict__ ug_w1, const float* __restrict__ ug_w2,
    const float* __restrict__ vo_w0, const float* __restrict__ vo_w1,
    const float* __restrict__ vq_w0, const float* __restrict__ vq_w1, const float* __restrict__ vq_w2,
    short* __restrict__ wt) {
  int t = blockIdx.x * blockDim.x + threadIdx.x;
  const float* W; int K, N, Kp; size_t base; int idx;
  if      (t < 73728)  { W = cm_w0; K = 160; N = 384; Kp = 192; base = WT_CM0; idx = t; }
  else if (t < 221184) { W = cm_w1; K = 384; N = 384; Kp = 384; base = WT_CM1; idx = t - 73728; }
  else if (t < 294912) { W = cm_w2; K = 384; N = 160; Kp = 384; base = WT_CM2; idx = t - 221184; }
  else if (t < 360448) { W = ug_w0; K = 224; N = 256; Kp = 256; base = WT_UG0; idx = t - 294912; }
  else if (t < 425984) { W = ug_w1; K = 256; N = 256; Kp = 256; base = WT_UG1; idx = t - 360448; }
  else if (t < 458752) { W = ug_w2; K = 256; N = 128; Kp = 256; base = WT_UG2; idx = t - 425984; }
  else if (t < 475136) { W = vo_w0; K = 128; N = 128; Kp = 128; base = WT_VO0; idx = t - 458752; }
  else if (t < 491520) { W = vo_w1; K = 128; N = 128; Kp = 128; base = WT_VO1; idx = t - 475136; }
  else if (t < 501760) { W = vq_w0; K = 132; N = 64;  Kp = 160; base = WT_VQ0; idx = t - 491520; }
  else if (t < 505856) { W = vq_w1; K = 64;  N = 64;  Kp = 64;  base = WT_VQ1; idx = t - 501760; }
  else if (t < 507904) { W = vq_w2; K = 64;  N = 32;  Kp = 64;  base = WT_VQ2; idx = t - 505856; }
  else return;
  int n = idx / Kp, k = idx - n * Kp;
  float v = (k < K && n < N) ? W[(size_t)k * N + n] : 0.f;
  wt[base + idx] = f2bf(v);
}

// ---------------- fused vq MLP: xugb[:, :128] (+noise) -> Q f32 ----------------
__global__ __launch_bounds__(256) void fused_vq_kernel(
    const short* __restrict__ xugb, const float* __restrict__ noise,
    const short* __restrict__ w0, const short* __restrict__ w1, const short* __restrict__ w2,
    const float* __restrict__ b0, const float* __restrict__ b1, const float* __restrict__ b2,
    float* __restrict__ Q) {
  __shared__ short A[64 * 160];
  __shared__ short H1[4][16 * 64];
  __shared__ short H2[4][16 * 64];
  const int wid = threadIdx.x >> 6, lane = threadIdx.x & 63;
  const int rbase = blockIdx.x * 64 + wid * 16;
  #pragma unroll
  for (int i = 0; i < 4; ++i) {
    int s = i * 64 + lane;
    int row = s >> 4, c8 = s & 15;
    *(bf16x8*)&A[(wid * 16 + row) * 160 + c8 * 8] =
        *(const bf16x8*)&xugb[(size_t)(rbase + row) * 256 + c8 * 8];
  }
  {
    int row = lane >> 2, seg = lane & 3;
    bf16x8 z = {0, 0, 0, 0, 0, 0, 0, 0};
    if (seg == 0) {
      float4 nz = *(const float4*)&noise[(size_t)(rbase + row) * 4];
      z[0] = f2bf(nz.x); z[1] = f2bf(nz.y); z[2] = f2bf(nz.z); z[3] = f2bf(nz.w);
    }
    *(bf16x8*)&A[(wid * 16 + row) * 160 + 128 + seg * 8] = z;
  }
  const int kof = (lane >> 4) * 8;
  const int l15 = lane & 15;
  f32x4 acc[4] = {};
  #pragma unroll
  for (int ks = 0; ks < 5; ++ks) {
    bf16x8 a = *(const bf16x8*)&A[(wid * 16 + l15) * 160 + ks * 32 + kof];
    #pragma unroll
    for (int ni = 0; ni < 4; ++ni) {
      bf16x8 b = *(const bf16x8*)&w0[(ni * 16 + l15) * 160 + ks * 32 + kof];
      acc[ni] = __builtin_amdgcn_mfma_f32_16x16x32_bf16(a, b, acc[ni], 0, 0, 0);
    }
  }
  #pragma unroll
  for (int ni = 0; ni < 4; ++ni) {
    int col = ni * 16 + l15;
    float bb = b0[col];
    #pragma unroll
    for (int j = 0; j < 4; ++j) {
      float v = acc[ni][j] + bb; v = v > 0.f ? v : 0.2f * v;
      H1[wid][((lane >> 4) * 4 + j) * 64 + col] = f2bf(v);
    }
  }
  f32x4 acc2[4] = {};
  #pragma unroll
  for (int ks = 0; ks < 2; ++ks) {
    bf16x8 a = *(const bf16x8*)&H1[wid][l15 * 64 + ks * 32 + kof];
    #pragma unroll
    for (int ni = 0; ni < 4; ++ni) {
      bf16x8 b = *(const bf16x8*)&w1[(ni * 16 + l15) * 64 + ks * 32 + kof];
      acc2[ni] = __builtin_amdgcn_mfma_f32_16x16x32_bf16(a, b, acc2[ni], 0, 0, 0);
    }
  }
  #pragma unroll
  for (int ni = 0; ni < 4; ++ni) {
    int col = ni * 16 + l15;
    float bb = b1[col];
    #pragma unroll
    for (int j = 0; j < 4; ++j) {
      float v = acc2[ni][j] + bb; v = v > 0.f ? v : 0.2f * v;
      H2[wid][((lane >> 4) * 4 + j) * 64 + col] = f2bf(v);
    }
  }
  f32x4 acc3[2] = {};
  #pragma unroll
  for (int ks = 0; ks < 2; ++ks) {
    bf16x8 a = *(const bf16x8*)&H2[wid][l15 * 64 + ks * 32 + kof];
    #pragma unroll
    for (int ni = 0; ni < 2; ++ni) {
      bf16x8 b = *(const bf16x8*)&w2[(ni * 16 + l15) * 64 + ks * 32 + kof];
      acc3[ni] = __builtin_amdgcn_mfma_f32_16x16x32_bf16(a, b, acc3[ni], 0, 0, 0);
    }
  }
  #pragma unroll
  for (int ni = 0; ni < 2; ++ni) {
    int col = ni * 16 + l15;
    float bb = b2[col];
    #pragma unroll
    for (int j = 0; j < 4; ++j)
      Q[(size_t)(rbase + (lane >> 4) * 4 + j) * 32 + col] = acc3[ni][j] + bb;
  }
}

// ---------------- clause_val -> xcmb bf16 tail; zero cmean/vmean ----------------
__global__ void fused_clause_kernel(const float* __restrict__ Q, const int* __restrict__ lit_var,
                                    const int* __restrict__ lit_sign,
                                    short* __restrict__ xcmb, float* __restrict__ meanz) {
  int t = blockIdx.x * blockDim.x + threadIdx.x;
  if (t < 2 * 32 * 128) meanz[t] = 0.f;
  if (t >= NCLS * 32) return;
  int c = t >> 5, m = t & 31;
  int l0 = 3 * c;
  int v0 = lit_var[l0], v1 = lit_var[l0 + 1], v2 = lit_var[l0 + 2];
  int s0 = lit_sign[l0], s1 = lit_sign[l0 + 1], s2 = lit_sign[l0 + 2];
  float q0 = Q[(size_t)v0 * 32 + m];
  float q1 = Q[(size_t)v1 * 32 + m];
  float q2 = Q[(size_t)v2 * 32 + m];
  float sp = softplus_f(q0 * (float)s0) + softplus_f(q1 * (float)s1) + softplus_f(q2 * (float)s2);
  float cl = expf(-sp);
  xcmb[(size_t)c * 192 + 128 + m] = f2bf(cl);
}

// ---------------- fused cm0+cm1: xcmb -> bufB (bf16 32768x384) ----------------
// 64 clause rows/block; waves 2x2 (wr=row-half 32, wc=col-half).
// LDS: Xs 64x200 (pad), H1s 64x392 (pad). Strides = 4 mod 32 dwords -> <=2-way conflicts.
__global__ __launch_bounds__(256) void fused_cm01_kernel(
    const short* __restrict__ xcmb,
    const short* __restrict__ w0, const short* __restrict__ w1,
    const float* __restrict__ b0, const float* __restrict__ b1,
    short* __restrict__ outB) {
  __shared__ short Xs[64 * 200];
  __shared__ short H1s[64 * 392];
  const int tid = threadIdx.x;
  const int wid = tid >> 6, lane = tid & 63;
  const int wr = (wid >> 1) * 32, wc = (wid & 1) * 192;
  const int rbase = blockIdx.x * 64;
  const int l15 = lane & 15;
  const int koff = (lane >> 4) * 8;

  // stage X: 64 rows x 192 cols = 1536 chunks of 8 bf16
  for (int i = 0; i < 6; ++i) {
    int c = i * 256 + tid;
    int row = c / 24, c8 = c - row * 24;
    bf16x8 v = *(const bf16x8*)&xcmb[(size_t)(rbase + row) * 192 + c8 * 8];
    *(bf16x8*)&Xs[row * 200 + c8 * 8] = v;
  }
  __syncthreads();

  // cm0: H1 = leaky(X @ W0t^T + b0), wave quadrant 32 rows x 192 cols
  {
    f32x4 acc[2][12] = {};
    #pragma unroll
    for (int kf = 0; kf < 6; ++kf) {
      bf16x8 a[2];
      #pragma unroll
      for (int mi = 0; mi < 2; ++mi)
        a[mi] = *(const bf16x8*)&Xs[(wr + mi * 16 + l15) * 200 + kf * 32 + koff];
      #pragma unroll
      for (int nf = 0; nf < 12; ++nf) {
        bf16x8 b = *(const bf16x8*)&w0[(size_t)(wc + nf * 16 + l15) * 192 + kf * 32 + koff];
        #pragma unroll
        for (int mi = 0; mi < 2; ++mi)
          acc[mi][nf] = __builtin_amdgcn_mfma_f32_16x16x32_bf16(a[mi], b, acc[mi][nf], 0, 0, 0);
      }
    }
    #pragma unroll
    for (int nf = 0; nf < 12; ++nf) {
      int col = wc + nf * 16 + l15;
      float bb = b0[col];
      #pragma unroll
      for (int mi = 0; mi < 2; ++mi)
        #pragma unroll
        for (int j = 0; j < 4; ++j) {
          float v = acc[mi][nf][j] + bb; v = v > 0.f ? v : 0.2f * v;
          H1s[(wr + mi * 16 + (lane >> 4) * 4 + j) * 392 + col] = f2bf(v);
        }
    }
  }
  __syncthreads();

  // cm1: out = leaky(H1 @ W1t^T + b1) -> global bufB
  {
    f32x4 acc[2][12] = {};
    #pragma unroll
    for (int kf = 0; kf < 12; ++kf) {
      bf16x8 a[2];
      #pragma unroll
      for (int mi = 0; mi < 2; ++mi)
        a[mi] = *(const bf16x8*)&H1s[(wr + mi * 16 + l15) * 392 + kf * 32 + koff];
      #pragma unroll
      for (int nf = 0; nf < 12; ++nf) {
        bf16x8 b = *(const bf16x8*)&w1[(size_t)(wc + nf * 16 + l15) * 384 + kf * 32 + koff];
        #pragma unroll
        for (int mi = 0; mi < 2; ++mi)
          acc[mi][nf] = __builtin_amdgcn_mfma_f32_16x16x32_bf16(a[mi], b, acc[mi][nf], 0, 0, 0);
      }
    }
    #pragma unroll
    for (int nf = 0; nf < 12; ++nf) {
      int col = wc + nf * 16 + l15;
      float bb = b1[col];
      #pragma unroll
      for (int mi = 0; mi < 2; ++mi)
        #pragma unroll
        for (int j = 0; j < 4; ++j) {
          float v = acc[mi][nf][j] + bb; v = v > 0.f ? v : 0.2f * v;
          int row = rbase + wr + mi * 16 + (lane >> 4) * 4 + j;
          outB[(size_t)row * 384 + col] = f2bf(v);
        }
    }
  }
}

// ---------------- fused ug0+ug1+ug2: xugb -> UO bf16 (CDb) + vmean ----------------
// 64 var rows/block; waves 2x2. LDS: Xs 64x264, Hs 64x264 (ping-pong, H2 overwrites Xs).
__global__ __launch_bounds__(256) void fused_ug012_kernel(
    const short* __restrict__ xugb,
    const short* __restrict__ w0, const short* __restrict__ w1, const short* __restrict__ w2,
    const float* __restrict__ b0, const float* __restrict__ b1, const float* __restrict__ b2,
    short* __restrict__ outB, float* __restrict__ vmean) {
  __shared__ short Xs[64 * 264];
  __shared__ short Hs[64 * 264];
  const int tid = threadIdx.x;
  const int wid = tid >> 6, lane = tid & 63;
  const int wr = (wid >> 1) * 32;
  const int wcH = (wid & 1) * 128;   // col-half for 256-wide layers
  const int l15 = lane & 15;
  const int koff = (lane >> 4) * 8;
  const int rbase = blockIdx.x * 64;

  // stage X: 64 rows x 256 cols = 2048 chunks
  for (int i = 0; i < 8; ++i) {
    int c = i * 256 + tid;
    int row = c >> 5, c8 = c & 31;
    bf16x8 v = *(const bf16x8*)&xugb[(size_t)(rbase + row) * 256 + c8 * 8];
    *(bf16x8*)&Xs[row * 264 + c8 * 8] = v;
  }
  __syncthreads();

  // ug0: H = leaky(X @ W0 + b0)
  {
    f32x4 acc[2][8] = {};
    #pragma unroll
    for (int kf = 0; kf < 8; ++kf) {
      bf16x8 a[2];
      #pragma unroll
      for (int mi = 0; mi < 2; ++mi)
        a[mi] = *(const bf16x8*)&Xs[(wr + mi * 16 + l15) * 264 + kf * 32 + koff];
      #pragma unroll
      for (int nf = 0; nf < 8; ++nf) {
        bf16x8 b = *(const bf16x8*)&w0[(size_t)(wcH + nf * 16 + l15) * 256 + kf * 32 + koff];
        #pragma unroll
        for (int mi = 0; mi < 2; ++mi)
          acc[mi][nf] = __builtin_amdgcn_mfma_f32_16x16x32_bf16(a[mi], b, acc[mi][nf], 0, 0, 0);
      }
    }
    #pragma unroll
    for (int nf = 0; nf < 8; ++nf) {
      int col = wcH + nf * 16 + l15;
      float bb = b0[col];
      #pragma unroll
      for (int mi = 0; mi < 2; ++mi)
        #pragma unroll
        for (int j = 0; j < 4; ++j) {
          float v = acc[mi][nf][j] + bb; v = v > 0.f ? v : 0.2f * v;
          Hs[(wr + mi * 16 + (lane >> 4) * 4 + j) * 264 + col] = f2bf(v);
        }
    }
  }
  __syncthreads();

  // ug1: H2 = leaky(H @ W1 + b1) -> overwrite Xs
  {
    f32x4 acc[2][8] = {};
    #pragma unroll
    for (int kf = 0; kf < 8; ++kf) {
      bf16x8 a[2];
      #pragma unroll
      for (int mi = 0; mi < 2; ++mi)
        a[mi] = *(const bf16x8*)&Hs[(wr + mi * 16 + l15) * 264 + kf * 32 + koff];
      #pragma unroll
      for (int nf = 0; nf < 8; ++nf) {
        bf16x8 b = *(const bf16x8*)&w1[(size_t)(wcH + nf * 16 + l15) * 256 + kf * 32 + koff];
        #pragma unroll
        for (int mi = 0; mi < 2; ++mi)
          acc[mi][nf] = __builtin_amdgcn_mfma_f32_16x16x32_bf16(a[mi], b, acc[mi][nf], 0, 0, 0);
      }
    }
    __syncthreads();   // everyone done reading Xs (ug0) before overwrite
    #pragma unroll
    for (int nf = 0; nf < 8; ++nf) {
      int col = wcH + nf * 16 + l15;
      float bb = b1[col];
      #pragma unroll
      for (int mi = 0; mi < 2; ++mi)
        #pragma unroll
        for (int j = 0; j < 4; ++j) {
          float v = acc[mi][nf][j] + bb; v = v > 0.f ? v : 0.2f * v;
          Xs[(wr + mi * 16 + (lane >> 4) * 4 + j) * 264 + col] = f2bf(v);
        }
    }
  }
  __syncthreads();

  // ug2: out = H2 @ W2 + b2 (no relu) -> global UO bf16 + vmean atomics
  {
    const int wcO = (wid & 1) * 64;   // N=128 col-half
    f32x4 acc[2][4] = {};
    #pragma unroll
    for (int kf = 0; kf < 8; ++kf) {
      bf16x8 a[2];
      #pragma unroll
      for (int mi = 0; mi < 2; ++mi)
        a[mi] = *(const bf16x8*)&Xs[(wr + mi * 16 + l15) * 264 + kf * 32 + koff];
      #pragma unroll
      for (int nf = 0; nf < 4; ++nf) {
        bf16x8 b = *(const bf16x8*)&w2[(size_t)(wcO + nf * 16 + l15) * 256 + kf * 32 + koff];
        #pragma unroll
        for (int mi = 0; mi < 2; ++mi)
          acc[mi][nf] = __builtin_amdgcn_mfma_f32_16x16x32_bf16(a[mi], b, acc[mi][nf], 0, 0, 0);
      }
    }
    int g = rbase >> 9;    // 512 rows per graph
    #pragma unroll
    for (int nf = 0; nf < 4; ++nf) {
      int col = wcO + nf * 16 + l15;
      float bb = b2[col];
      float colsum = 0.f;
      #pragma unroll
      for (int mi = 0; mi < 2; ++mi)
        #pragma unroll
        for (int j = 0; j < 4; ++j) {
          float v = acc[mi][nf][j] + bb;
          int row = rbase + wr + mi * 16 + (lane >> 4) * 4 + j;
          outB[(size_t)row * 128 + col] = f2bf(v);
          colsum += v;
        }
      colsum += __shfl_xor(colsum, 16);
      colsum += __shfl_xor(colsum, 32);
      if ((lane >> 4) == 0)
        atomicAdd(&vmean[(size_t)g * 128 + col], colsum * (1.f / 512.f));
    }
  }
}

// ---------------- bf16 MFMA GEMM template (cm2 only, EPI1) ----------------
template<int TN, bool RELU, bool OUTBF16, int EPI>
__global__ __launch_bounds__(256) void gemm_mfma_kernel(
    const short* __restrict__ A, int lda,
    const short* __restrict__ Wt,
    const float* __restrict__ bias, int nbias,
    void* __restrict__ Cout, int Np, int Kp,
    short* __restrict__ aux,
    float* __restrict__ meanbuf, float inv_cnt, int gshift) {
  constexpr int NB = TN / 32;
  __shared__ short As[128 * 64];
  __shared__ short Bs[TN * 64];
  const int bn = blockIdx.x * TN;
  const int bm = blockIdx.y * 128;
  const int tid  = threadIdx.x;
  const int wid  = tid >> 6;
  const int lane = tid & 63;
  const int wm = (wid >> 1) * 64;
  const int wn = (wid & 1) * (TN / 2);

  f32x4 acc[4][NB] = {};

  for (int k0 = 0; k0 < Kp; k0 += 64) {
    #pragma unroll
    for (int i = 0; i < 4; ++i) {
      int s = (i * 4 + wid) * 64 + lane;
      int row = s >> 3, cs = (s & 7) << 3;
      const short* src = A + (size_t)(bm + row) * lda + k0 + cs;
      __builtin_amdgcn_global_load_lds(
          (const __attribute__((address_space(1))) void*)src,
          (__attribute__((address_space(3))) void*)(As + (size_t)(i * 4 + wid) * 64 * 8),
          16, 0, 0);
    }
    #pragma unroll
    for (int i = 0; i < TN / 32; ++i) {
      int s = (i * 4 + wid) * 64 + lane;
      int n = s >> 3, cs = (s & 7) << 3;
      const short* src = Wt + (size_t)(bn + n) * Kp + k0 + cs;
      __builtin_amdgcn_global_load_lds(
          (const __attribute__((address_space(1))) void*)src,
          (__attribute__((address_space(3))) void*)(Bs + (size_t)(i * 4 + wid) * 64 * 8),
          16, 0, 0);
    }
    __syncthreads();

    #pragma unroll
    for (int ks = 0; ks < 2; ++ks) {
      const int kof = ks * 32 + (lane >> 4) * 8;
      bf16x8 a[4], b[NB];
      #pragma unroll
      for (int mi = 0; mi < 4; ++mi)
        a[mi] = *(const bf16x8*)&As[(wm + mi * 16 + (lane & 15)) * 64 + kof];
      #pragma unroll
      for (int ni = 0; ni < NB; ++ni)
        b[ni] = *(const bf16x8*)&Bs[(wn + ni * 16 + (lane & 15)) * 64 + kof];
      #pragma unroll
      for (int mi = 0; mi < 4; ++mi)
        #pragma unroll
        for (int ni = 0; ni < NB; ++ni)
          acc[mi][ni] = __builtin_amdgcn_mfma_f32_16x16x32_bf16(a[mi], b[ni], acc[mi][ni], 0, 0, 0);
    }
    __syncthreads();
  }

  const int col0 = bn + wn + (lane & 15);
  const int row0 = bm + wm + (lane >> 4) * 4;
  #pragma unroll
  for (int ni = 0; ni < NB; ++ni) {
    int col = col0 + ni * 16;
    float bv = (col < nbias) ? bias[col] : 0.f;
    float colsum = 0.f;
    #pragma unroll
    for (int mi = 0; mi < 4; ++mi) {
      #pragma unroll
      for (int j = 0; j < 4; ++j) {
        int row = row0 + mi * 16 + j;
        float v = acc[mi][ni][j] + bv;
        if (EPI == 0) {
          if (RELU) v = v > 0.f ? v : 0.2f * v;
          if (OUTBF16) ((short*)Cout)[(size_t)row * Np + col] = f2bf(v);
          else         ((float*)Cout)[(size_t)row * Np + col] = v;
        } else if (EPI == 1) {
          if (col < 32) {
            aux[(size_t)row * 32 + col] = f2bf(v);
          } else if (col < 160) {
            ((short*)Cout)[(size_t)row * Np + col] = f2bf(v);
            colsum += v;
          }
        } else {
          ((short*)Cout)[(size_t)row * Np + col] = f2bf(v);
          colsum += v;
        }
      }
    }
    if ((EPI == 1 && col >= 32 && col < 160) || EPI == 2) {
      colsum += __shfl_xor(colsum, 16);
      colsum += __shfl_xor(colsum, 32);
      if ((lane >> 4) == 0) {
        int midx = (EPI == 1) ? (col - 32) : col;
        atomicAdd(&meanbuf[(size_t)(bm >> gshift) * 128 + midx], colsum * inv_cnt);
      }
    }
  }
}

// ---------------- merged: pairnorm_c (+state) AND vg/lp/ln gather -> xugb ----------------
__global__ __launch_bounds__(256) void pnc_gather_kernel(
    const short* __restrict__ CDb, const float* __restrict__ cmean,
    float* __restrict__ cst, short* __restrict__ xcmb,
    const float* __restrict__ Q, const int* __restrict__ cso, const int* __restrict__ cse,
    const short* __restrict__ vloss, short* __restrict__ xugb) {
  int b = blockIdx.x;
  if (b < NCLS / 4) {
    int wid = threadIdx.x >> 6;
    int lane = threadIdx.x & 63;
    int row = b * 4 + wid;
    int g = row >> 10;
    const short* xp = CDb + (size_t)row * 192 + 32;
    float y0 = bf2f(xp[lane])      - cmean[g * 128 + lane];
    float y1 = bf2f(xp[lane + 64]) - cmean[g * 128 + lane + 64];
    float ss = y0 * y0 + y1 * y1;
    #pragma unroll
    for (int o = 32; o > 0; o >>= 1) ss += __shfl_xor(ss, o);
    float inv = rsqrtf(ss * (1.f / 128.f) + 1e-6f);
    float* sp = cst + (size_t)row * 128;
    float s0 = y0 * inv * 0.25f + 0.1f * sp[lane];
    float s1 = y1 * inv * 0.25f + 0.1f * sp[lane + 64];
    sp[lane]      = s0;
    sp[lane + 64] = s1;
    xcmb[(size_t)row * 192 + lane]      = f2bf(s0);
    xcmb[(size_t)row * 192 + lane + 64] = f2bf(s1);
  } else {
    int t = (b - NCLS / 4) * 256 + threadIdx.x;
    int v = t >> 5, m = t & 31;
    float q = Q[(size_t)v * 32 + m];
    float sig = 1.f / (1.f + expf(-q));
    float vgs = 0.f, lps = 0.f, lns = 0.f;
    int e0 = cso[v], e1 = cso[v + 1];
    for (int e = e0; e < e1; ++e) {
      int ent = cse[e];
      int c = ent >> 1;
      bool pos = ent & 1;
      float clc = bf2f(xcmb[(size_t)c * 192 + 128 + m]);
      vgs -= clc * (sig - (pos ? 0.f : 1.f));
      float vl = bf2f(vloss[(size_t)c * 32 + m]);
      if (pos) lps += vl; else lns += vl;
    }
    short* xp = xugb + (size_t)v * 256 + 128;
    xp[m]      = f2bf(vgs);
    xp[32 + m] = f2bf(lps);
    xp[64 + m] = f2bf(lns);
  }
}

// ---------------- pair_norm + state update + bf16 copy (variables) ----------------
__global__ __launch_bounds__(256) void pairnorm_update_kernel(
    const short* __restrict__ x, int stride, int coloff,
    const float* __restrict__ mean, float* __restrict__ state,
    short* __restrict__ bout, int bstride, int rows_per_g) {
  int wid = threadIdx.x >> 6;
  int lane = threadIdx.x & 63;
  int row = blockIdx.x * 4 + wid;
  int g = row / rows_per_g;
  const short* xp = x + (size_t)row * stride + coloff;
  float y0 = bf2f(xp[lane])      - mean[g * 128 + lane];
  float y1 = bf2f(xp[lane + 64]) - mean[g * 128 + lane + 64];
  float ss = y0 * y0 + y1 * y1;
  #pragma unroll
  for (int o = 32; o > 0; o >>= 1) ss += __shfl_xor(ss, o);
  float inv = rsqrtf(ss * (1.f / 128.f) + 1e-6f);
  float* sp = state + (size_t)row * 128;
  float s0 = y0 * inv * 0.25f + 0.1f * sp[lane];
  float s1 = y1 * inv * 0.25f + 0.1f * sp[lane + 64];
  sp[lane]      = s0;
  sp[lane + 64] = s1;
  bout[(size_t)row * bstride + lane]      = f2bf(s0);
  bout[(size_t)row * bstride + lane + 64] = f2bf(s1);
}

// ---------------- fused vo MLP: xugb[:, :128] -> logits f32 ----------------
__global__ __launch_bounds__(256) void fused_vo_kernel(
    const short* __restrict__ xugb,
    const short* __restrict__ w0, const short* __restrict__ w1,
    const float* __restrict__ b0, const float* __restrict__ b1,
    const float* __restrict__ w2, const float* __restrict__ b2,
    float* __restrict__ logits) {
  __shared__ short A[64 * 128];
  __shared__ short H1[4][16 * 128];
  __shared__ short H2[4][16 * 128];
  const int wid = threadIdx.x >> 6, lane = threadIdx.x & 63;
  const int rbase = blockIdx.x * 64 + wid * 16;
  #pragma unroll
  for (int i = 0; i < 4; ++i) {
    int s = i * 64 + lane;
    int row = s >> 4, c8 = s & 15;
    *(bf16x8*)&A[(wid * 16 + row) * 128 + c8 * 8] =
        *(const bf16x8*)&xugb[(size_t)(rbase + row) * 256 + c8 * 8];
  }
  const int kof = (lane >> 4) * 8;
  const int l15 = lane & 15;
  f32x4 acc[8] = {};
  #pragma unroll
  for (int ks = 0; ks < 4; ++ks) {
    bf16x8 a = *(const bf16x8*)&A[(wid * 16 + l15) * 128 + ks * 32 + kof];
    #pragma unroll
    for (int ni = 0; ni < 8; ++ni) {
      bf16x8 b = *(const bf16x8*)&w0[(ni * 16 + l15) * 128 + ks * 32 + kof];
      acc[ni] = __builtin_amdgcn_mfma_f32_16x16x32_bf16(a, b, acc[ni], 0, 0, 0);
    }
  }
  #pragma unroll
  for (int ni = 0; ni < 8; ++ni) {
    int col = ni * 16 + l15;
    float bb = b0[col];
    #pragma unroll
    for (int j = 0; j < 4; ++j) {
      float v = acc[ni][j] + bb; v = v > 0.f ? v : 0.2f * v;
      H1[wid][((lane >> 4) * 4 + j) * 128 + col] = f2bf(v);
    }
  }
  f32x4 acc2[8] = {};
  #pragma unroll
  for (int ks = 0; ks < 4; ++ks) {
    bf16x8 a = *(const bf16x8*)&H1[wid][l15 * 128 + ks * 32 + kof];
    #pragma unroll
    for (int ni = 0; ni < 8; ++ni) {
      bf16x8 b = *(const bf16x8*)&w1[(ni * 16 + l15) * 128 + ks * 32 + kof];
      acc2[ni] = __builtin_amdgcn_mfma_f32_16x16x32_bf16(a, b, acc2[ni], 0, 0, 0);
    }
  }
  #pragma unroll
  for (int ni = 0; ni < 8; ++ni) {
    int col = ni * 16 + l15;
    float bb = b1[col];
    #pragma unroll
    for (int j = 0; j < 4; ++j) {
      float v = acc2[ni][j] + bb; v = v > 0.f ? v : 0.2f * v;
      H2[wid][((lane >> 4) * 4 + j) * 128 + col] = f2bf(v);
    }
  }
  {
    int row = lane >> 2, q = lane & 3;
    float s = 0.f;
    #pragma unroll
    for (int jj = 0; jj < 4; ++jj) {
      bf16x8 h = *(const bf16x8*)&H2[wid][row * 128 + q * 32 + jj * 8];
      #pragma unroll
      for (int e = 0; e < 8; ++e) s += bf2f(h[e]) * w2[q * 32 + jj * 8 + e];
    }
    s += __shfl_xor(s, 1);
    s += __shfl_xor(s, 2);
    if (q == 0) logits[rbase + row] = s + b2[0];
  }
}

// ---------------- per-clause loss + per-graph sqrt reduce ----------------
__global__ __launch_bounds__(1024) void fused_loss_kernel(
    const float* __restrict__ logits, const int* __restrict__ lit_var,
    const int* __restrict__ lit_sign, float* __restrict__ loss) {
  __shared__ float lg[512];
  __shared__ float red[16];
  int g = blockIdx.x, tid = threadIdx.x;
  if (tid < 512) lg[tid] = logits[(size_t)g * 512 + tid];
  __syncthreads();
  int c = g * 1024 + tid;
  float s = 0.f;
  #pragma unroll
  for (int i = 0; i < 3; ++i) {
    int l = 3 * c + i;
    float sg = (float)lit_sign[l];
    s += softplus_f(lg[lit_var[l] - g * 512] * sg);
  }
  float vv = expf(-s);
  float pcv = vv * (-logf(1.f - vv + 1e-8f));
  #pragma unroll
  for (int o = 32; o > 0; o >>= 1) pcv += __shfl_xor(pcv, o);
  if ((tid & 63) == 0) red[tid >> 6] = pcv;
  __syncthreads();
  if (tid < 16) {
    float x = red[tid];
    #pragma unroll
    for (int o = 8; o > 0; o >>= 1) x += __shfl_xor(x, o);
    if (tid == 0) atomicAdd(loss, sqrtf(x + 1e-6f));
  }
}

__global__ void finalize_kernel(const float* __restrict__ loss_acc, float* __restrict__ out) {
  out[0] = loss_acc[0] * 0.25f;
}

// =======================================================================
extern "C" void kernel_launch(void* const* d_in, const int* in_sizes, int n_in,
                              void* d_out, int out_size, void* d_ws, size_t ws_size,
                              hipStream_t stream) {
  const int* lit_var    = (const int*)d_in[0];
  const int* lit_sign   = (const int*)d_in[1];
  const int* lit_clause = (const int*)d_in[2];
  const float* noise    = (const float*)d_in[5];
  const float* vq_w0 = (const float*)d_in[6];   const float* vq_b0 = (const float*)d_in[7];
  const float* vq_w1 = (const float*)d_in[8];   const float* vq_b1 = (const float*)d_in[9];
  const float* vq_w2 = (const float*)d_in[10];  const float* vq_b2 = (const float*)d_in[11];
  const float* cm_w0 = (const float*)d_in[12];  const float* cm_b0 = (const float*)d_in[13];
  const float* cm_w1 = (const float*)d_in[14];  const float* cm_b1 = (const float*)d_in[15];
  const float* cm_w2 = (const float*)d_in[16];  const float* cm_b2 = (const float*)d_in[17];
  const float* ug_w0 = (const float*)d_in[18];  const float* ug_b0 = (const float*)d_in[19];
  const float* ug_w1 = (const float*)d_in[20];  const float* ug_b1 = (const float*)d_in[21];
  const float* ug_w2 = (const float*)d_in[22];  const float* ug_b2 = (const float*)d_in[23];
  const float* vo_w0 = (const float*)d_in[24];  const float* vo_b0 = (const float*)d_in[25];
  const float* vo_w1 = (const float*)d_in[26];  const float* vo_b1 = (const float*)d_in[27];
  const float* vo_w2 = (const float*)d_in[28];  const float* vo_b2 = (const float*)d_in[29];

  float* ws = (float*)d_ws;
  float* var   = ws + OFF_VAR;
  float* cst   = ws + OFF_CST;
  short* xcmb  = (short*)(ws + OFF_XCMB);
  short* xugb  = (short*)(ws + OFF_XUGB);
  short* bufB  = (short*)(ws + OFF_BBUF);
  short* CDb   = (short*)(ws + OFF_CD);
  float* Q     = ws + OFF_Q;
  short* vloss = (short*)(ws + OFF_VLOSS);
  float* cmean = ws + OFF_CMEAN;
  float* vmean = ws + OFF_VMEAN;
  float* loss  = ws + OFF_LOSS;
  int*   cso   = (int*)(ws + OFF_CSO);
  int*   cse   = (int*)(ws + OFF_CSE);
  int*   csc   = (int*)(ws + OFF_CSC);
  short* wt    = (short*)(ws + OFF_WT);
  float* logits = (float*)d_out;
  float* loss_out = (float*)d_out + NVARS;

  convert_all_kernel<<<1984, 256, 0, stream>>>(cm_w0, cm_w1, cm_w2, ug_w0, ug_w1, ug_w2,
                                               vo_w0, vo_w1, vq_w0, vq_w1, vq_w2, wt);
  init_state_kernel<<<30784, 256, 0, stream>>>(var, cst, xugb, xcmb, loss, csc);
  csr_count_kernel<<<NLITS / 256, 256, 0, stream>>>(lit_var, csc);
  csr_scan_kernel<<<1, 1024, 0, stream>>>(csc, cso, csc);
  csr_fill_kernel<<<NLITS / 256, 256, 0, stream>>>(lit_var, lit_sign, lit_clause, csc, cse);

  for (int r = 0; r < NROUNDS; ++r) {
    const float* noise_r = noise + (size_t)r * NVARS * 4;

    // vq MLP -> Q
    fused_vq_kernel<<<NVARS / 64, 256, 0, stream>>>(
        xugb, noise_r, wt + WT_VQ0, wt + WT_VQ1, wt + WT_VQ2, vq_b0, vq_b1, vq_b2, Q);

    // clause_val -> xcmb bf16; zero means
    fused_clause_kernel<<<NCLS * 32 / 256, 256, 0, stream>>>(Q, lit_var, lit_sign, xcmb, cmean);

    // cm0+cm1 fused -> bufB
    fused_cm01_kernel<<<NCLS / 64, 256, 0, stream>>>(
        xcmb, wt + WT_CM0, wt + WT_CM1, cm_b0, cm_b1, bufB);

    // cm2 (EPI1: vloss + CD bf16 + cmean)
    gemm_mfma_kernel<64, false, false, 1><<<dim3(3, NCLS / 128), 256, 0, stream>>>(
        bufB, 384, wt + WT_CM2, cm_b2, 160, CDb, 192, 384, vloss, cmean, 1.f / 1024.f, 10);

    // pairnorm_c + gather (vg/lp/ln -> xugb cols 128..223)
    pnc_gather_kernel<<<NCLS / 4 + NVARS * 32 / 256, 256, 0, stream>>>(
        CDb, cmean, cst, xcmb, Q, cso, cse, vloss, xugb);

    // ug0+ug1+ug2 fused -> UO bf16 (CDb) + vmean
    fused_ug012_kernel<<<NVARS / 64, 256, 0, stream>>>(
        xugb, wt + WT_UG0, wt + WT_UG1, wt + WT_UG2, ug_b0, ug_b1, ug_b2, CDb, vmean);

    // variables pair_norm update
    pairnorm_update_kernel<<<NVARS / 4, 256, 0, stream>>>(CDb, 128, 0, vmean, var, xugb, 256, 512);

    // vo MLP -> logits
    fused_vo_kernel<<<NVARS / 64, 256, 0, stream>>>(
        xugb, wt + WT_VO0, wt + WT_VO1, vo_b0, vo_b1, vo_w2, vo_b2, logits);

    // loss
    fused_loss_kernel<<<NG, 1024, 0, stream>>>(logits, lit_var, lit_sign, loss);
  }

  finalize_kernel<<<1, 1, 0, stream>>>(loss, loss_out);
}

// Round 10
// 673.211 us; speedup vs baseline: 1.1232x; 1.1232x over previous
//
#include <hip/hip_runtime.h>
#include <hip/hip_bf16.h>
#include <math.h>

#define NG     32
#define NVARS  16384
#define NCLS   32768
#define NLITS  98304
#define NROUNDS 4

typedef __attribute__((ext_vector_type(8))) short bf16x8;
typedef __attribute__((ext_vector_type(4))) float f32x4;

// ---------------- workspace layout (float units) ----------------
#define OFF_VAR    ((size_t)0)            // f32 16384x128
#define OFF_CST    ((size_t)2097152)      // f32 32768x128
#define OFF_XCMB   ((size_t)6291456)      // bf16 32768x192
#define OFF_XUGB   ((size_t)9437184)      // bf16 16384x256
#define OFF_ABUF   ((size_t)11534336)     // bf16 32768x384
#define OFF_BBUF   ((size_t)17825792)     // bf16 32768x384
#define OFF_CD     ((size_t)24117248)     // bf16 32768x192 (also UO 16384x128 bf16)
#define OFF_Q      ((size_t)30408704)     // f32 16384x32
#define OFF_VLOSS  ((size_t)31981568)     // bf16 32768x32
#define OFF_CMEAN  ((size_t)33030144)     // f32 32x128 (cmean+vmean contiguous)
#define OFF_VMEAN  ((size_t)33034240)     // f32 32x128
#define OFF_LOSS   ((size_t)33038336)     // f32 1
#define OFF_CSO    ((size_t)33038340)     // int 16385
#define OFF_CSE    ((size_t)33054725)     // int 98304 ((clause<<1)|pos)
#define OFF_CSC    ((size_t)33153029)     // int 16384
#define OFF_WT     ((size_t)33169416)     // bf16 pool 507904 elems

#define WT_CM0  ((size_t)0)       // [384][192]
#define WT_CM1  ((size_t)73728)   // [384][384]
#define WT_CM2  ((size_t)221184)  // [192][384]
#define WT_UG0  ((size_t)294912)  // [256][256]
#define WT_UG1  ((size_t)360448)  // [256][256]
#define WT_UG2  ((size_t)425984)  // [128][256]
#define WT_VO0  ((size_t)458752)  // [128][128]
#define WT_VO1  ((size_t)475136)  // [128][128]
#define WT_VQ0  ((size_t)491520)  // [64][160]
#define WT_VQ1  ((size_t)501760)  // [64][64]
#define WT_VQ2  ((size_t)505856)  // [32][64]

__device__ __forceinline__ float softplus_f(float x) {
  return fmaxf(x, 0.f) + log1pf(expf(-fabsf(x)));
}
__device__ __forceinline__ short f2bf(float x) {
  __hip_bfloat16 h = __float2bfloat16(x);
  return *reinterpret_cast<short*>(&h);
}
__device__ __forceinline__ float bf2f(short s) {
  __hip_bfloat16 h = *reinterpret_cast<__hip_bfloat16*>(&s);
  return __bfloat162float(h);
}

// ---------------- init ----------------
__global__ void init_state_kernel(float* __restrict__ var, float* __restrict__ cst,
                                  short* __restrict__ xugb, short* __restrict__ xcmb,
                                  float* __restrict__ loss, int* __restrict__ cnt) {
  int t = blockIdx.x * blockDim.x + threadIdx.x;
  if (t == 0) *loss = 0.f;
  const int main_total = (NVARS + NCLS) * 128;
  if (t < main_total) {
    int row = t >> 7, m = t & 127;
    const float base = 2.82842712474619f; // sqrt(128)*0.25
    float val = ((m == 0) ? (1.f - 1.f / 128.f) : (-1.f / 128.f)) * base;
    if (row < NVARS) {
      var[(size_t)row * 128 + m] = val;
      xugb[(size_t)row * 256 + m] = f2bf(val);
    } else {
      int c = row - NVARS;
      cst[(size_t)c * 128 + m] = val;
      xcmb[(size_t)c * 192 + m] = f2bf(val);
    }
    return;
  }
  int t2 = t - main_total;
  if (t2 < NVARS * 32) {           // xugb cols 224..255 = 0 forever
    int row = t2 >> 5, j = t2 & 31;
    xugb[(size_t)row * 256 + 224 + j] = 0;
    return;
  }
  int t3 = t2 - NVARS * 32;
  if (t3 < NCLS * 32) {            // xcmb cols 160..191 = 0 forever
    int row = t3 >> 5, j = t3 & 31;
    xcmb[(size_t)row * 192 + 160 + j] = 0;
    return;
  }
  int t4 = t3 - NCLS * 32;
  if (t4 < NVARS) cnt[t4] = 0;
}

// ---------------- CSR build ----------------
__global__ void csr_count_kernel(const int* __restrict__ lit_var, int* __restrict__ cnt) {
  int l = blockIdx.x * blockDim.x + threadIdx.x;
  if (l >= NLITS) return;
  atomicAdd(&cnt[lit_var[l]], 1);
}

__global__ __launch_bounds__(1024) void csr_scan_kernel(const int* __restrict__ cnt,
                                                        int* __restrict__ cso,
                                                        int* __restrict__ cur) {
  __shared__ int part[1024];
  int t = threadIdx.x;
  int base = t * 16;
  int local[16];
  int s = 0;
  #pragma unroll
  for (int i = 0; i < 16; ++i) { local[i] = cnt[base + i]; s += local[i]; }
  part[t] = s;
  __syncthreads();
  for (int off = 1; off < 1024; off <<= 1) {
    int v = (t >= off) ? part[t - off] : 0;
    __syncthreads();
    part[t] += v;
    __syncthreads();
  }
  int run = part[t] - s;
  #pragma unroll
  for (int i = 0; i < 16; ++i) {
    cso[base + i] = run;
    cur[base + i] = run;
    run += local[i];
  }
  if (t == 1023) cso[NVARS] = run;
}

__global__ void csr_fill_kernel(const int* __restrict__ lit_var, const int* __restrict__ lit_sign,
                                const int* __restrict__ lit_clause,
                                int* __restrict__ cur, int* __restrict__ cse) {
  int l = blockIdx.x * blockDim.x + threadIdx.x;
  if (l >= NLITS) return;
  int v = lit_var[l];
  int pos = atomicAdd(&cur[v], 1);
  cse[pos] = (lit_clause[l] << 1) | (lit_sign[l] > 0 ? 1 : 0);
}

// ---------------- weight convert ----------------
__global__ void convert_all_kernel(
    const float* __restrict__ cm_w0, const float* __restrict__ cm_w1, const float* __restrict__ cm_w2,
    const float* __restrict__ ug_w0, const float* __restrict__ ug_w1, const float* __restrict__ ug_w2,
    const float* __restrict__ vo_w0, const float* __restrict__ vo_w1,
    const float* __restrict__ vq_w0, const float* __restrict__ vq_w1, const float* __restrict__ vq_w2,
    short* __restrict__ wt) {
  int t = blockIdx.x * blockDim.x + threadIdx.x;
  const float* W; int K, N, Kp; size_t base; int idx;
  if      (t < 73728)  { W = cm_w0; K = 160; N = 384; Kp = 192; base = WT_CM0; idx = t; }
  else if (t < 221184) { W = cm_w1; K = 384; N = 384; Kp = 384; base = WT_CM1; idx = t - 73728; }
  else if (t < 294912) { W = cm_w2; K = 384; N = 160; Kp = 384; base = WT_CM2; idx = t - 221184; }
  else if (t < 360448) { W = ug_w0; K = 224; N = 256; Kp = 256; base = WT_UG0; idx = t - 294912; }
  else if (t < 425984) { W = ug_w1; K = 256; N = 256; Kp = 256; base = WT_UG1; idx = t - 360448; }
  else if (t < 458752) { W = ug_w2; K = 256; N = 128; Kp = 256; base = WT_UG2; idx = t - 425984; }
  else if (t < 475136) { W = vo_w0; K = 128; N = 128; Kp = 128; base = WT_VO0; idx = t - 458752; }
  else if (t < 491520) { W = vo_w1; K = 128; N = 128; Kp = 128; base = WT_VO1; idx = t - 475136; }
  else if (t < 501760) { W = vq_w0; K = 132; N = 64;  Kp = 160; base = WT_VQ0; idx = t - 491520; }
  else if (t < 505856) { W = vq_w1; K = 64;  N = 64;  Kp = 64;  base = WT_VQ1; idx = t - 501760; }
  else if (t < 507904) { W = vq_w2; K = 64;  N = 32;  Kp = 64;  base = WT_VQ2; idx = t - 505856; }
  else return;
  int n = idx / Kp, k = idx - n * Kp;
  float v = (k < K && n < N) ? W[(size_t)k * N + n] : 0.f;
  wt[base + idx] = f2bf(v);
}

// ---------------- fused vq MLP: xugb[:, :128] (+noise) -> Q f32 ----------------
__global__ __launch_bounds__(256) void fused_vq_kernel(
    const short* __restrict__ xugb, const float* __restrict__ noise,
    const short* __restrict__ w0, const short* __restrict__ w1, const short* __restrict__ w2,
    const float* __restrict__ b0, const float* __restrict__ b1, const float* __restrict__ b2,
    float* __restrict__ Q) {
  __shared__ short A[64 * 160];
  __shared__ short H1[4][16 * 64];
  __shared__ short H2[4][16 * 64];
  const int wid = threadIdx.x >> 6, lane = threadIdx.x & 63;
  const int rbase = blockIdx.x * 64 + wid * 16;
  #pragma unroll
  for (int i = 0; i < 4; ++i) {
    int s = i * 64 + lane;
    int row = s >> 4, c8 = s & 15;
    *(bf16x8*)&A[(wid * 16 + row) * 160 + c8 * 8] =
        *(const bf16x8*)&xugb[(size_t)(rbase + row) * 256 + c8 * 8];
  }
  {
    int row = lane >> 2, seg = lane & 3;
    bf16x8 z = {0, 0, 0, 0, 0, 0, 0, 0};
    if (seg == 0) {
      float4 nz = *(const float4*)&noise[(size_t)(rbase + row) * 4];
      z[0] = f2bf(nz.x); z[1] = f2bf(nz.y); z[2] = f2bf(nz.z); z[3] = f2bf(nz.w);
    }
    *(bf16x8*)&A[(wid * 16 + row) * 160 + 128 + seg * 8] = z;
  }
  const int kof = (lane >> 4) * 8;
  const int l15 = lane & 15;
  f32x4 acc[4] = {};
  #pragma unroll
  for (int ks = 0; ks < 5; ++ks) {
    bf16x8 a = *(const bf16x8*)&A[(wid * 16 + l15) * 160 + ks * 32 + kof];
    #pragma unroll
    for (int ni = 0; ni < 4; ++ni) {
      bf16x8 b = *(const bf16x8*)&w0[(ni * 16 + l15) * 160 + ks * 32 + kof];
      acc[ni] = __builtin_amdgcn_mfma_f32_16x16x32_bf16(a, b, acc[ni], 0, 0, 0);
    }
  }
  #pragma unroll
  for (int ni = 0; ni < 4; ++ni) {
    int col = ni * 16 + l15;
    float bb = b0[col];
    #pragma unroll
    for (int j = 0; j < 4; ++j) {
      float v = acc[ni][j] + bb; v = v > 0.f ? v : 0.2f * v;
      H1[wid][((lane >> 4) * 4 + j) * 64 + col] = f2bf(v);
    }
  }
  f32x4 acc2[4] = {};
  #pragma unroll
  for (int ks = 0; ks < 2; ++ks) {
    bf16x8 a = *(const bf16x8*)&H1[wid][l15 * 64 + ks * 32 + kof];
    #pragma unroll
    for (int ni = 0; ni < 4; ++ni) {
      bf16x8 b = *(const bf16x8*)&w1[(ni * 16 + l15) * 64 + ks * 32 + kof];
      acc2[ni] = __builtin_amdgcn_mfma_f32_16x16x32_bf16(a, b, acc2[ni], 0, 0, 0);
    }
  }
  #pragma unroll
  for (int ni = 0; ni < 4; ++ni) {
    int col = ni * 16 + l15;
    float bb = b1[col];
    #pragma unroll
    for (int j = 0; j < 4; ++j) {
      float v = acc2[ni][j] + bb; v = v > 0.f ? v : 0.2f * v;
      H2[wid][((lane >> 4) * 4 + j) * 64 + col] = f2bf(v);
    }
  }
  f32x4 acc3[2] = {};
  #pragma unroll
  for (int ks = 0; ks < 2; ++ks) {
    bf16x8 a = *(const bf16x8*)&H2[wid][l15 * 64 + ks * 32 + kof];
    #pragma unroll
    for (int ni = 0; ni < 2; ++ni) {
      bf16x8 b = *(const bf16x8*)&w2[(ni * 16 + l15) * 64 + ks * 32 + kof];
      acc3[ni] = __builtin_amdgcn_mfma_f32_16x16x32_bf16(a, b, acc3[ni], 0, 0, 0);
    }
  }
  #pragma unroll
  for (int ni = 0; ni < 2; ++ni) {
    int col = ni * 16 + l15;
    float bb = b2[col];
    #pragma unroll
    for (int j = 0; j < 4; ++j)
      Q[(size_t)(rbase + (lane >> 4) * 4 + j) * 32 + col] = acc3[ni][j] + bb;
  }
}

// ---------------- clause_val -> xcmb bf16 tail; zero cmean/vmean ----------------
__global__ void fused_clause_kernel(const float* __restrict__ Q, const int* __restrict__ lit_var,
                                    const int* __restrict__ lit_sign,
                                    short* __restrict__ xcmb, float* __restrict__ meanz) {
  int t = blockIdx.x * blockDim.x + threadIdx.x;
  if (t < 2 * 32 * 128) meanz[t] = 0.f;
  if (t >= NCLS * 32) return;
  int c = t >> 5, m = t & 31;
  int l0 = 3 * c;
  int v0 = lit_var[l0], v1 = lit_var[l0 + 1], v2 = lit_var[l0 + 2];
  int s0 = lit_sign[l0], s1 = lit_sign[l0 + 1], s2 = lit_sign[l0 + 2];
  float q0 = Q[(size_t)v0 * 32 + m];
  float q1 = Q[(size_t)v1 * 32 + m];
  float q2 = Q[(size_t)v2 * 32 + m];
  float sp = softplus_f(q0 * (float)s0) + softplus_f(q1 * (float)s1) + softplus_f(q2 * (float)s2);
  float cl = expf(-sp);
  xcmb[(size_t)c * 192 + 128 + m] = f2bf(cl);
}

// ---------------- bf16 MFMA GEMM template ----------------
// EPI 0: plain. EPI 1: cm2 (vloss bf16 cols<32; CD bf16 cols 32..159 + cmean).
// EPI 2: ug2 (bf16 out all cols + vmean).
template<int TN, bool RELU, bool OUTBF16, int EPI>
__global__ __launch_bounds__(256) void gemm_mfma_kernel(
    const short* __restrict__ A, int lda,
    const short* __restrict__ Wt,
    const float* __restrict__ bias, int nbias,
    void* __restrict__ Cout, int Np, int Kp,
    short* __restrict__ aux,
    float* __restrict__ meanbuf, float inv_cnt, int gshift) {
  constexpr int NB = TN / 32;
  __shared__ short As[128 * 64];
  __shared__ short Bs[TN * 64];
  const int bn = blockIdx.x * TN;
  const int bm = blockIdx.y * 128;
  const int tid  = threadIdx.x;
  const int wid  = tid >> 6;
  const int lane = tid & 63;
  const int wm = (wid >> 1) * 64;
  const int wn = (wid & 1) * (TN / 2);

  f32x4 acc[4][NB] = {};

  for (int k0 = 0; k0 < Kp; k0 += 64) {
    #pragma unroll
    for (int i = 0; i < 4; ++i) {
      int s = (i * 4 + wid) * 64 + lane;
      int row = s >> 3, cs = (s & 7) << 3;
      const short* src = A + (size_t)(bm + row) * lda + k0 + cs;
      __builtin_amdgcn_global_load_lds(
          (const __attribute__((address_space(1))) void*)src,
          (__attribute__((address_space(3))) void*)(As + (size_t)(i * 4 + wid) * 64 * 8),
          16, 0, 0);
    }
    #pragma unroll
    for (int i = 0; i < TN / 32; ++i) {
      int s = (i * 4 + wid) * 64 + lane;
      int n = s >> 3, cs = (s & 7) << 3;
      const short* src = Wt + (size_t)(bn + n) * Kp + k0 + cs;
      __builtin_amdgcn_global_load_lds(
          (const __attribute__((address_space(1))) void*)src,
          (__attribute__((address_space(3))) void*)(Bs + (size_t)(i * 4 + wid) * 64 * 8),
          16, 0, 0);
    }
    __syncthreads();

    #pragma unroll
    for (int ks = 0; ks < 2; ++ks) {
      const int kof = ks * 32 + (lane >> 4) * 8;
      bf16x8 a[4], b[NB];
      #pragma unroll
      for (int mi = 0; mi < 4; ++mi)
        a[mi] = *(const bf16x8*)&As[(wm + mi * 16 + (lane & 15)) * 64 + kof];
      #pragma unroll
      for (int ni = 0; ni < NB; ++ni)
        b[ni] = *(const bf16x8*)&Bs[(wn + ni * 16 + (lane & 15)) * 64 + kof];
      #pragma unroll
      for (int mi = 0; mi < 4; ++mi)
        #pragma unroll
        for (int ni = 0; ni < NB; ++ni)
          acc[mi][ni] = __builtin_amdgcn_mfma_f32_16x16x32_bf16(a[mi], b[ni], acc[mi][ni], 0, 0, 0);
    }
    __syncthreads();
  }

  const int col0 = bn + wn + (lane & 15);
  const int row0 = bm + wm + (lane >> 4) * 4;
  #pragma unroll
  for (int ni = 0; ni < NB; ++ni) {
    int col = col0 + ni * 16;
    float bv = (col < nbias) ? bias[col] : 0.f;
    float colsum = 0.f;
    #pragma unroll
    for (int mi = 0; mi < 4; ++mi) {
      #pragma unroll
      for (int j = 0; j < 4; ++j) {
        int row = row0 + mi * 16 + j;
        float v = acc[mi][ni][j] + bv;
        if (EPI == 0) {
          if (RELU) v = v > 0.f ? v : 0.2f * v;
          if (OUTBF16) ((short*)Cout)[(size_t)row * Np + col] = f2bf(v);
          else         ((float*)Cout)[(size_t)row * Np + col] = v;
        } else if (EPI == 1) {
          if (col < 32) {
            aux[(size_t)row * 32 + col] = f2bf(v);       // vloss bf16
          } else if (col < 160) {
            ((short*)Cout)[(size_t)row * Np + col] = f2bf(v);
            colsum += v;
          }
        } else {  // EPI == 2
          ((short*)Cout)[(size_t)row * Np + col] = f2bf(v);
          colsum += v;
        }
      }
    }
    if ((EPI == 1 && col >= 32 && col < 160) || EPI == 2) {
      colsum += __shfl_xor(colsum, 16);
      colsum += __shfl_xor(colsum, 32);
      if ((lane >> 4) == 0) {
        int midx = (EPI == 1) ? (col - 32) : col;
        atomicAdd(&meanbuf[(size_t)(bm >> gshift) * 128 + midx], colsum * inv_cnt);
      }
    }
  }
}

// ---------------- merged: pairnorm_c (+state) AND vg/lp/ln gather -> xugb ----------------
__global__ __launch_bounds__(256) void pnc_gather_kernel(
    const short* __restrict__ CDb, const float* __restrict__ cmean,
    float* __restrict__ cst, short* __restrict__ xcmb,
    const float* __restrict__ Q, const int* __restrict__ cso, const int* __restrict__ cse,
    const short* __restrict__ vloss, short* __restrict__ xugb) {
  int b = blockIdx.x;
  if (b < NCLS / 4) {
    int wid = threadIdx.x >> 6;
    int lane = threadIdx.x & 63;
    int row = b * 4 + wid;
    int g = row >> 10;
    const short* xp = CDb + (size_t)row * 192 + 32;
    float y0 = bf2f(xp[lane])      - cmean[g * 128 + lane];
    float y1 = bf2f(xp[lane + 64]) - cmean[g * 128 + lane + 64];
    float ss = y0 * y0 + y1 * y1;
    #pragma unroll
    for (int o = 32; o > 0; o >>= 1) ss += __shfl_xor(ss, o);
    float inv = rsqrtf(ss * (1.f / 128.f) + 1e-6f);
    float* sp = cst + (size_t)row * 128;
    float s0 = y0 * inv * 0.25f + 0.1f * sp[lane];
    float s1 = y1 * inv * 0.25f + 0.1f * sp[lane + 64];
    sp[lane]      = s0;
    sp[lane + 64] = s1;
    xcmb[(size_t)row * 192 + lane]      = f2bf(s0);
    xcmb[(size_t)row * 192 + lane + 64] = f2bf(s1);
  } else {
    int t = (b - NCLS / 4) * 256 + threadIdx.x;
    int v = t >> 5, m = t & 31;
    float q = Q[(size_t)v * 32 + m];
    float sig = 1.f / (1.f + expf(-q));
    float vgs = 0.f, lps = 0.f, lns = 0.f;
    int e0 = cso[v], e1 = cso[v + 1];
    for (int e = e0; e < e1; ++e) {
      int ent = cse[e];
      int c = ent >> 1;
      bool pos = ent & 1;
      float clc = bf2f(xcmb[(size_t)c * 192 + 128 + m]);
      vgs -= clc * (sig - (pos ? 0.f : 1.f));
      float vl = bf2f(vloss[(size_t)c * 32 + m]);
      if (pos) lps += vl; else lns += vl;
    }
    short* xp = xugb + (size_t)v * 256 + 128;
    xp[m]      = f2bf(vgs);
    xp[32 + m] = f2bf(lps);
    xp[64 + m] = f2bf(lns);
  }
}

// ---------------- pair_norm + state update + bf16 copy (variables) ----------------
__global__ __launch_bounds__(256) void pairnorm_update_kernel(
    const short* __restrict__ x, int stride, int coloff,
    const float* __restrict__ mean, float* __restrict__ state,
    short* __restrict__ bout, int bstride, int rows_per_g) {
  int wid = threadIdx.x >> 6;
  int lane = threadIdx.x & 63;
  int row = blockIdx.x * 4 + wid;
  int g = row / rows_per_g;
  const short* xp = x + (size_t)row * stride + coloff;
  float y0 = bf2f(xp[lane])      - mean[g * 128 + lane];
  float y1 = bf2f(xp[lane + 64]) - mean[g * 128 + lane + 64];
  float ss = y0 * y0 + y1 * y1;
  #pragma unroll
  for (int o = 32; o > 0; o >>= 1) ss += __shfl_xor(ss, o);
  float inv = rsqrtf(ss * (1.f / 128.f) + 1e-6f);
  float* sp = state + (size_t)row * 128;
  float s0 = y0 * inv * 0.25f + 0.1f * sp[lane];
  float s1 = y1 * inv * 0.25f + 0.1f * sp[lane + 64];
  sp[lane]      = s0;
  sp[lane + 64] = s1;
  bout[(size_t)row * bstride + lane]      = f2bf(s0);
  bout[(size_t)row * bstride + lane + 64] = f2bf(s1);
}

// ---------------- fused vo MLP: xugb[:, :128] -> logits f32 ----------------
__global__ __launch_bounds__(256) void fused_vo_kernel(
    const short* __restrict__ xugb,
    const short* __restrict__ w0, const short* __restrict__ w1,
    const float* __restrict__ b0, const float* __restrict__ b1,
    const float* __restrict__ w2, const float* __restrict__ b2,
    float* __restrict__ logits) {
  __shared__ short A[64 * 128];
  __shared__ short H1[4][16 * 128];
  __shared__ short H2[4][16 * 128];
  const int wid = threadIdx.x >> 6, lane = threadIdx.x & 63;
  const int rbase = blockIdx.x * 64 + wid * 16;
  #pragma unroll
  for (int i = 0; i < 4; ++i) {
    int s = i * 64 + lane;
    int row = s >> 4, c8 = s & 15;
    *(bf16x8*)&A[(wid * 16 + row) * 128 + c8 * 8] =
        *(const bf16x8*)&xugb[(size_t)(rbase + row) * 256 + c8 * 8];
  }
  const int kof = (lane >> 4) * 8;
  const int l15 = lane & 15;
  f32x4 acc[8] = {};
  #pragma unroll
  for (int ks = 0; ks < 4; ++ks) {
    bf16x8 a = *(const bf16x8*)&A[(wid * 16 + l15) * 128 + ks * 32 + kof];
    #pragma unroll
    for (int ni = 0; ni < 8; ++ni) {
      bf16x8 b = *(const bf16x8*)&w0[(ni * 16 + l15) * 128 + ks * 32 + kof];
      acc[ni] = __builtin_amdgcn_mfma_f32_16x16x32_bf16(a, b, acc[ni], 0, 0, 0);
    }
  }
  #pragma unroll
  for (int ni = 0; ni < 8; ++ni) {
    int col = ni * 16 + l15;
    float bb = b0[col];
    #pragma unroll
    for (int j = 0; j < 4; ++j) {
      float v = acc[ni][j] + bb; v = v > 0.f ? v : 0.2f * v;
      H1[wid][((lane >> 4) * 4 + j) * 128 + col] = f2bf(v);
    }
  }
  f32x4 acc2[8] = {};
  #pragma unroll
  for (int ks = 0; ks < 4; ++ks) {
    bf16x8 a = *(const bf16x8*)&H1[wid][l15 * 128 + ks * 32 + kof];
    #pragma unroll
    for (int ni = 0; ni < 8; ++ni) {
      bf16x8 b = *(const bf16x8*)&w1[(ni * 16 + l15) * 128 + ks * 32 + kof];
      acc2[ni] = __builtin_amdgcn_mfma_f32_16x16x32_bf16(a, b, acc2[ni], 0, 0, 0);
    }
  }
  #pragma unroll
  for (int ni = 0; ni < 8; ++ni) {
    int col = ni * 16 + l15;
    float bb = b1[col];
    #pragma unroll
    for (int j = 0; j < 4; ++j) {
      float v = acc2[ni][j] + bb; v = v > 0.f ? v : 0.2f * v;
      H2[wid][((lane >> 4) * 4 + j) * 128 + col] = f2bf(v);
    }
  }
  {
    int row = lane >> 2, q = lane & 3;
    float s = 0.f;
    #pragma unroll
    for (int jj = 0; jj < 4; ++jj) {
      bf16x8 h = *(const bf16x8*)&H2[wid][row * 128 + q * 32 + jj * 8];
      #pragma unroll
      for (int e = 0; e < 8; ++e) s += bf2f(h[e]) * w2[q * 32 + jj * 8 + e];
    }
    s += __shfl_xor(s, 1);
    s += __shfl_xor(s, 2);
    if (q == 0) logits[rbase + row] = s + b2[0];
  }
}

// ---------------- per-clause loss + per-graph sqrt reduce ----------------
__global__ __launch_bounds__(1024) void fused_loss_kernel(
    const float* __restrict__ logits, const int* __restrict__ lit_var,
    const int* __restrict__ lit_sign, float* __restrict__ loss) {
  __shared__ float lg[512];
  __shared__ float red[16];
  int g = blockIdx.x, tid = threadIdx.x;
  if (tid < 512) lg[tid] = logits[(size_t)g * 512 + tid];
  __syncthreads();
  int c = g * 1024 + tid;
  float s = 0.f;
  #pragma unroll
  for (int i = 0; i < 3; ++i) {
    int l = 3 * c + i;
    float sg = (float)lit_sign[l];
    s += softplus_f(lg[lit_var[l] - g * 512] * sg);
  }
  float vv = expf(-s);
  float pcv = vv * (-logf(1.f - vv + 1e-8f));
  #pragma unroll
  for (int o = 32; o > 0; o >>= 1) pcv += __shfl_xor(pcv, o);
  if ((tid & 63) == 0) red[tid >> 6] = pcv;
  __syncthreads();
  if (tid < 16) {
    float x = red[tid];
    #pragma unroll
    for (int o = 8; o > 0; o >>= 1) x += __shfl_xor(x, o);
    if (tid == 0) atomicAdd(loss, sqrtf(x + 1e-6f));
  }
}

__global__ void finalize_kernel(const float* __restrict__ loss_acc, float* __restrict__ out) {
  out[0] = loss_acc[0] * 0.25f;
}

// =======================================================================
extern "C" void kernel_launch(void* const* d_in, const int* in_sizes, int n_in,
                              void* d_out, int out_size, void* d_ws, size_t ws_size,
                              hipStream_t stream) {
  const int* lit_var    = (const int*)d_in[0];
  const int* lit_sign   = (const int*)d_in[1];
  const int* lit_clause = (const int*)d_in[2];
  const float* noise    = (const float*)d_in[5];
  const float* vq_w0 = (const float*)d_in[6];   const float* vq_b0 = (const float*)d_in[7];
  const float* vq_w1 = (const float*)d_in[8];   const float* vq_b1 = (const float*)d_in[9];
  const float* vq_w2 = (const float*)d_in[10];  const float* vq_b2 = (const float*)d_in[11];
  const float* cm_w0 = (const float*)d_in[12];  const float* cm_b0 = (const float*)d_in[13];
  const float* cm_w1 = (const float*)d_in[14];  const float* cm_b1 = (const float*)d_in[15];
  const float* cm_w2 = (const float*)d_in[16];  const float* cm_b2 = (const float*)d_in[17];
  const float* ug_w0 = (const float*)d_in[18];  const float* ug_b0 = (const float*)d_in[19];
  const float* ug_w1 = (const float*)d_in[20];  const float* ug_b1 = (const float*)d_in[21];
  const float* ug_w2 = (const float*)d_in[22];  const float* ug_b2 = (const float*)d_in[23];
  const float* vo_w0 = (const float*)d_in[24];  const float* vo_b0 = (const float*)d_in[25];
  const float* vo_w1 = (const float*)d_in[26];  const float* vo_b1 = (const float*)d_in[27];
  const float* vo_w2 = (const float*)d_in[28];  const float* vo_b2 = (const float*)d_in[29];

  float* ws = (float*)d_ws;
  float* var   = ws + OFF_VAR;
  float* cst   = ws + OFF_CST;
  short* xcmb  = (short*)(ws + OFF_XCMB);
  short* xugb  = (short*)(ws + OFF_XUGB);
  short* bufA  = (short*)(ws + OFF_ABUF);
  short* bufB  = (short*)(ws + OFF_BBUF);
  short* CDb   = (short*)(ws + OFF_CD);
  float* Q     = ws + OFF_Q;
  short* vloss = (short*)(ws + OFF_VLOSS);
  float* cmean = ws + OFF_CMEAN;
  float* vmean = ws + OFF_VMEAN;
  float* loss  = ws + OFF_LOSS;
  int*   cso   = (int*)(ws + OFF_CSO);
  int*   cse   = (int*)(ws + OFF_CSE);
  int*   csc   = (int*)(ws + OFF_CSC);
  short* wt    = (short*)(ws + OFF_WT);
  float* logits = (float*)d_out;
  float* loss_out = (float*)d_out + NVARS;

  convert_all_kernel<<<1984, 256, 0, stream>>>(cm_w0, cm_w1, cm_w2, ug_w0, ug_w1, ug_w2,
                                               vo_w0, vo_w1, vq_w0, vq_w1, vq_w2, wt);
  init_state_kernel<<<30784, 256, 0, stream>>>(var, cst, xugb, xcmb, loss, csc);
  csr_count_kernel<<<NLITS / 256, 256, 0, stream>>>(lit_var, csc);
  csr_scan_kernel<<<1, 1024, 0, stream>>>(csc, cso, csc);
  csr_fill_kernel<<<NLITS / 256, 256, 0, stream>>>(lit_var, lit_sign, lit_clause, csc, cse);

  for (int r = 0; r < NROUNDS; ++r) {
    const float* noise_r = noise + (size_t)r * NVARS * 4;

    // vq MLP -> Q
    fused_vq_kernel<<<NVARS / 64, 256, 0, stream>>>(
        xugb, noise_r, wt + WT_VQ0, wt + WT_VQ1, wt + WT_VQ2, vq_b0, vq_b1, vq_b2, Q);

    // clause_val -> xcmb bf16; zero means
    fused_clause_kernel<<<NCLS * 32 / 256, 256, 0, stream>>>(Q, lit_var, lit_sign, xcmb, cmean);

    // cm MLP
    gemm_mfma_kernel<128, true, true, 0><<<dim3(3, NCLS / 128), 256, 0, stream>>>(
        xcmb, 192, wt + WT_CM0, cm_b0, 384, bufA, 384, 192, nullptr, nullptr, 0.f, 0);
    gemm_mfma_kernel<128, true, true, 0><<<dim3(3, NCLS / 128), 256, 0, stream>>>(
        bufA, 384, wt + WT_CM1, cm_b1, 384, bufB, 384, 384, nullptr, nullptr, 0.f, 0);
    gemm_mfma_kernel<64, false, false, 1><<<dim3(3, NCLS / 128), 256, 0, stream>>>(
        bufB, 384, wt + WT_CM2, cm_b2, 160, CDb, 192, 384, vloss, cmean, 1.f / 1024.f, 10);

    // pairnorm_c + gather (vg/lp/ln -> xugb cols 128..223)
    pnc_gather_kernel<<<NCLS / 4 + NVARS * 32 / 256, 256, 0, stream>>>(
        CDb, cmean, cst, xcmb, Q, cso, cse, vloss, xugb);

    // ug MLP
    gemm_mfma_kernel<128, true, true, 0><<<dim3(2, NVARS / 128), 256, 0, stream>>>(
        xugb, 256, wt + WT_UG0, ug_b0, 256, bufA, 256, 256, nullptr, nullptr, 0.f, 0);
    gemm_mfma_kernel<128, true, true, 0><<<dim3(2, NVARS / 128), 256, 0, stream>>>(
        bufA, 256, wt + WT_UG1, ug_b1, 256, bufB, 256, 256, nullptr, nullptr, 0.f, 0);
    gemm_mfma_kernel<64, false, false, 2><<<dim3(2, NVARS / 128), 256, 0, stream>>>(
        bufB, 256, wt + WT_UG2, ug_b2, 128, CDb, 128, 256, nullptr, vmean, 1.f / 512.f, 9);

    // variables pair_norm update (reads bf16 UO in CDb)
    pairnorm_update_kernel<<<NVARS / 4, 256, 0, stream>>>(CDb, 128, 0, vmean, var, xugb, 256, 512);

    // vo MLP -> logits
    fused_vo_kernel<<<NVARS / 64, 256, 0, stream>>>(
        xugb, wt + WT_VO0, wt + WT_VO1, vo_b0, vo_b1, vo_w2, vo_b2, logits);

    // loss
    fused_loss_kernel<<<NG, 1024, 0, stream>>>(logits, lit_var, lit_sign, loss);
  }

  finalize_kernel<<<1, 1, 0, stream>>>(loss, loss_out);
}

// Round 11
// 654.294 us; speedup vs baseline: 1.1556x; 1.0289x over previous
//
#include <hip/hip_runtime.h>
#include <hip/hip_bf16.h>
#include <math.h>

#define NG     32
#define NVARS  16384
#define NCLS   32768
#define NLITS  98304
#define NROUNDS 4

typedef __attribute__((ext_vector_type(8))) short bf16x8;
typedef __attribute__((ext_vector_type(4))) float f32x4;

// ---------------- workspace layout (float units) ----------------
#define OFF_CLVL   ((size_t)0)            // bf16 32768x64: cols 0..31 = cl, 32..63 = vloss
#define OFF_XCMB   ((size_t)6291456)      // bf16 32768x192 (cols 0..127 = clause state)
#define OFF_XUGB   ((size_t)9437184)      // bf16 16384x256 (cols 0..127 = variable state)
#define OFF_ABUF   ((size_t)11534336)     // bf16 32768x384
#define OFF_BBUF   ((size_t)17825792)     // bf16 32768x384
#define OFF_CD     ((size_t)24117248)     // bf16 32768x192 (also UO 16384x128 bf16)
#define OFF_Q      ((size_t)30408704)     // f32 16384x32
#define OFF_CMEAN  ((size_t)33030144)     // f32 32x128 (cmean+vmean contiguous)
#define OFF_VMEAN  ((size_t)33034240)     // f32 32x128
#define OFF_LOSS   ((size_t)33038336)     // f32 1
#define OFF_CSO    ((size_t)33038340)     // int 16385
#define OFF_CSE    ((size_t)33054725)     // int 98304 ((clause<<1)|pos)
#define OFF_CSC    ((size_t)33153029)     // int 16384
#define OFF_WT     ((size_t)33169416)     // bf16 pool 507904 elems

#define WT_CM0  ((size_t)0)       // [384][192]
#define WT_CM1  ((size_t)73728)   // [384][384]
#define WT_CM2  ((size_t)221184)  // [192][384]
#define WT_UG0  ((size_t)294912)  // [256][256]
#define WT_UG1  ((size_t)360448)  // [256][256]
#define WT_UG2  ((size_t)425984)  // [128][256]
#define WT_VO0  ((size_t)458752)  // [128][128]
#define WT_VO1  ((size_t)475136)  // [128][128]
#define WT_VQ0  ((size_t)491520)  // [64][160]
#define WT_VQ1  ((size_t)501760)  // [64][64]
#define WT_VQ2  ((size_t)505856)  // [32][64]

__device__ __forceinline__ float softplus_f(float x) {
  return fmaxf(x, 0.f) + log1pf(expf(-fabsf(x)));
}
__device__ __forceinline__ short f2bf(float x) {
  __hip_bfloat16 h = __float2bfloat16(x);
  return *reinterpret_cast<short*>(&h);
}
__device__ __forceinline__ float bf2f(short s) {
  __hip_bfloat16 h = *reinterpret_cast<__hip_bfloat16*>(&s);
  return __bfloat162float(h);
}

// ---------------- init: bf16 states + constant pads + loss=0 + csr cnt=0 ----------------
__global__ void init_state_kernel(short* __restrict__ xugb, short* __restrict__ xcmb,
                                  float* __restrict__ loss, int* __restrict__ cnt) {
  int t = blockIdx.x * blockDim.x + threadIdx.x;
  if (t == 0) *loss = 0.f;
  const int main_total = (NVARS + NCLS) * 128;
  if (t < main_total) {
    int row = t >> 7, m = t & 127;
    const float base = 2.82842712474619f; // sqrt(128)*0.25
    float val = ((m == 0) ? (1.f - 1.f / 128.f) : (-1.f / 128.f)) * base;
    if (row < NVARS) xugb[(size_t)row * 256 + m] = f2bf(val);
    else             xcmb[(size_t)(row - NVARS) * 192 + m] = f2bf(val);
    return;
  }
  int t2 = t - main_total;
  if (t2 < NVARS * 32) {           // xugb cols 224..255 = 0 forever
    int row = t2 >> 5, j = t2 & 31;
    xugb[(size_t)row * 256 + 224 + j] = 0;
    return;
  }
  int t3 = t2 - NVARS * 32;
  if (t3 < NCLS * 32) {            // xcmb cols 160..191 = 0 forever
    int row = t3 >> 5, j = t3 & 31;
    xcmb[(size_t)row * 192 + 160 + j] = 0;
    return;
  }
  int t4 = t3 - NCLS * 32;
  if (t4 < NVARS) cnt[t4] = 0;
}

// ---------------- CSR build ----------------
__global__ void csr_count_kernel(const int* __restrict__ lit_var, int* __restrict__ cnt) {
  int l = blockIdx.x * blockDim.x + threadIdx.x;
  if (l >= NLITS) return;
  atomicAdd(&cnt[lit_var[l]], 1);
}

__global__ __launch_bounds__(1024) void csr_scan_kernel(const int* __restrict__ cnt,
                                                        int* __restrict__ cso,
                                                        int* __restrict__ cur) {
  __shared__ int part[1024];
  int t = threadIdx.x;
  int base = t * 16;
  int local[16];
  int s = 0;
  #pragma unroll
  for (int i = 0; i < 16; ++i) { local[i] = cnt[base + i]; s += local[i]; }
  part[t] = s;
  __syncthreads();
  for (int off = 1; off < 1024; off <<= 1) {
    int v = (t >= off) ? part[t - off] : 0;
    __syncthreads();
    part[t] += v;
    __syncthreads();
  }
  int run = part[t] - s;
  #pragma unroll
  for (int i = 0; i < 16; ++i) {
    cso[base + i] = run;
    cur[base + i] = run;
    run += local[i];
  }
  if (t == 1023) cso[NVARS] = run;
}

__global__ void csr_fill_kernel(const int* __restrict__ lit_var, const int* __restrict__ lit_sign,
                                const int* __restrict__ lit_clause,
                                int* __restrict__ cur, int* __restrict__ cse) {
  int l = blockIdx.x * blockDim.x + threadIdx.x;
  if (l >= NLITS) return;
  int v = lit_var[l];
  int pos = atomicAdd(&cur[v], 1);
  cse[pos] = (lit_clause[l] << 1) | (lit_sign[l] > 0 ? 1 : 0);
}

// ---------------- weight convert ----------------
__global__ void convert_all_kernel(
    const float* __restrict__ cm_w0, const float* __restrict__ cm_w1, const float* __restrict__ cm_w2,
    const float* __restrict__ ug_w0, const float* __restrict__ ug_w1, const float* __restrict__ ug_w2,
    const float* __restrict__ vo_w0, const float* __restrict__ vo_w1,
    const float* __restrict__ vq_w0, const float* __restrict__ vq_w1, const float* __restrict__ vq_w2,
    short* __restrict__ wt) {
  int t = blockIdx.x * blockDim.x + threadIdx.x;
  const float* W; int K, N, Kp; size_t base; int idx;
  if      (t < 73728)  { W = cm_w0; K = 160; N = 384; Kp = 192; base = WT_CM0; idx = t; }
  else if (t < 221184) { W = cm_w1; K = 384; N = 384; Kp = 384; base = WT_CM1; idx = t - 73728; }
  else if (t < 294912) { W = cm_w2; K = 384; N = 160; Kp = 384; base = WT_CM2; idx = t - 221184; }
  else if (t < 360448) { W = ug_w0; K = 224; N = 256; Kp = 256; base = WT_UG0; idx = t - 294912; }
  else if (t < 425984) { W = ug_w1; K = 256; N = 256; Kp = 256; base = WT_UG1; idx = t - 360448; }
  else if (t < 458752) { W = ug_w2; K = 256; N = 128; Kp = 256; base = WT_UG2; idx = t - 425984; }
  else if (t < 475136) { W = vo_w0; K = 128; N = 128; Kp = 128; base = WT_VO0; idx = t - 458752; }
  else if (t < 491520) { W = vo_w1; K = 128; N = 128; Kp = 128; base = WT_VO1; idx = t - 475136; }
  else if (t < 501760) { W = vq_w0; K = 132; N = 64;  Kp = 160; base = WT_VQ0; idx = t - 491520; }
  else if (t < 505856) { W = vq_w1; K = 64;  N = 64;  Kp = 64;  base = WT_VQ1; idx = t - 501760; }
  else if (t < 507904) { W = vq_w2; K = 64;  N = 32;  Kp = 64;  base = WT_VQ2; idx = t - 505856; }
  else return;
  int n = idx / Kp, k = idx - n * Kp;
  float v = (k < K && n < N) ? W[(size_t)k * N + n] : 0.f;
  wt[base + idx] = f2bf(v);
}

// ---------------- fused vq MLP: xugb[:, :128] (+noise) -> Q f32 ----------------
__global__ __launch_bounds__(256) void fused_vq_kernel(
    const short* __restrict__ xugb, const float* __restrict__ noise,
    const short* __restrict__ w0, const short* __restrict__ w1, const short* __restrict__ w2,
    const float* __restrict__ b0, const float* __restrict__ b1, const float* __restrict__ b2,
    float* __restrict__ Q) {
  __shared__ short A[64 * 160];
  __shared__ short H1[4][16 * 64];
  __shared__ short H2[4][16 * 64];
  const int wid = threadIdx.x >> 6, lane = threadIdx.x & 63;
  const int rbase = blockIdx.x * 64 + wid * 16;
  #pragma unroll
  for (int i = 0; i < 4; ++i) {
    int s = i * 64 + lane;
    int row = s >> 4, c8 = s & 15;
    *(bf16x8*)&A[(wid * 16 + row) * 160 + c8 * 8] =
        *(const bf16x8*)&xugb[(size_t)(rbase + row) * 256 + c8 * 8];
  }
  {
    int row = lane >> 2, seg = lane & 3;
    bf16x8 z = {0, 0, 0, 0, 0, 0, 0, 0};
    if (seg == 0) {
      float4 nz = *(const float4*)&noise[(size_t)(rbase + row) * 4];
      z[0] = f2bf(nz.x); z[1] = f2bf(nz.y); z[2] = f2bf(nz.z); z[3] = f2bf(nz.w);
    }
    *(bf16x8*)&A[(wid * 16 + row) * 160 + 128 + seg * 8] = z;
  }
  const int kof = (lane >> 4) * 8;
  const int l15 = lane & 15;
  f32x4 acc[4] = {};
  #pragma unroll
  for (int ks = 0; ks < 5; ++ks) {
    bf16x8 a = *(const bf16x8*)&A[(wid * 16 + l15) * 160 + ks * 32 + kof];
    #pragma unroll
    for (int ni = 0; ni < 4; ++ni) {
      bf16x8 b = *(const bf16x8*)&w0[(ni * 16 + l15) * 160 + ks * 32 + kof];
      acc[ni] = __builtin_amdgcn_mfma_f32_16x16x32_bf16(a, b, acc[ni], 0, 0, 0);
    }
  }
  #pragma unroll
  for (int ni = 0; ni < 4; ++ni) {
    int col = ni * 16 + l15;
    float bb = b0[col];
    #pragma unroll
    for (int j = 0; j < 4; ++j) {
      float v = acc[ni][j] + bb; v = v > 0.f ? v : 0.2f * v;
      H1[wid][((lane >> 4) * 4 + j) * 64 + col] = f2bf(v);
    }
  }
  f32x4 acc2[4] = {};
  #pragma unroll
  for (int ks = 0; ks < 2; ++ks) {
    bf16x8 a = *(const bf16x8*)&H1[wid][l15 * 64 + ks * 32 + kof];
    #pragma unroll
    for (int ni = 0; ni < 4; ++ni) {
      bf16x8 b = *(const bf16x8*)&w1[(ni * 16 + l15) * 64 + ks * 32 + kof];
      acc2[ni] = __builtin_amdgcn_mfma_f32_16x16x32_bf16(a, b, acc2[ni], 0, 0, 0);
    }
  }
  #pragma unroll
  for (int ni = 0; ni < 4; ++ni) {
    int col = ni * 16 + l15;
    float bb = b1[col];
    #pragma unroll
    for (int j = 0; j < 4; ++j) {
      float v = acc2[ni][j] + bb; v = v > 0.f ? v : 0.2f * v;
      H2[wid][((lane >> 4) * 4 + j) * 64 + col] = f2bf(v);
    }
  }
  f32x4 acc3[2] = {};
  #pragma unroll
  for (int ks = 0; ks < 2; ++ks) {
    bf16x8 a = *(const bf16x8*)&H2[wid][l15 * 64 + ks * 32 + kof];
    #pragma unroll
    for (int ni = 0; ni < 2; ++ni) {
      bf16x8 b = *(const bf16x8*)&w2[(ni * 16 + l15) * 64 + ks * 32 + kof];
      acc3[ni] = __builtin_amdgcn_mfma_f32_16x16x32_bf16(a, b, acc3[ni], 0, 0, 0);
    }
  }
  #pragma unroll
  for (int ni = 0; ni < 2; ++ni) {
    int col = ni * 16 + l15;
    float bb = b2[col];
    #pragma unroll
    for (int j = 0; j < 4; ++j)
      Q[(size_t)(rbase + (lane >> 4) * 4 + j) * 32 + col] = acc3[ni][j] + bb;
  }
}

// ---------------- clause_val -> clvl[:, :32] + xcmb tail; zero cmean/vmean ----------------
__global__ void fused_clause_kernel(const float* __restrict__ Q, const int* __restrict__ lit_var,
                                    const int* __restrict__ lit_sign,
                                    short* __restrict__ xcmb, short* __restrict__ clvl,
                                    float* __restrict__ meanz) {
  int t = blockIdx.x * blockDim.x + threadIdx.x;
  if (t < 2 * 32 * 128) meanz[t] = 0.f;
  if (t >= NCLS * 32) return;
  int c = t >> 5, m = t & 31;
  int l0 = 3 * c;
  int v0 = lit_var[l0], v1 = lit_var[l0 + 1], v2 = lit_var[l0 + 2];
  int s0 = lit_sign[l0], s1 = lit_sign[l0 + 1], s2 = lit_sign[l0 + 2];
  float q0 = Q[(size_t)v0 * 32 + m];
  float q1 = Q[(size_t)v1 * 32 + m];
  float q2 = Q[(size_t)v2 * 32 + m];
  float sp = softplus_f(q0 * (float)s0) + softplus_f(q1 * (float)s1) + softplus_f(q2 * (float)s2);
  float cl = expf(-sp);
  short clb = f2bf(cl);
  xcmb[(size_t)c * 192 + 128 + m] = clb;
  clvl[(size_t)c * 64 + m] = clb;
}

// ---------------- bf16 MFMA GEMM template ----------------
// EPI 0: plain. EPI 1: cm2 (vloss bf16 -> clvl cols 32..63; CD bf16 cols 32..159 + cmean).
// EPI 2: ug2 (bf16 out all cols + vmean).
template<int TN, bool RELU, bool OUTBF16, int EPI>
__global__ __launch_bounds__(256) void gemm_mfma_kernel(
    const short* __restrict__ A, int lda,
    const short* __restrict__ Wt,
    const float* __restrict__ bias, int nbias,
    void* __restrict__ Cout, int Np, int Kp,
    short* __restrict__ aux,
    float* __restrict__ meanbuf, float inv_cnt, int gshift) {
  constexpr int NB = TN / 32;
  __shared__ short As[128 * 64];
  __shared__ short Bs[TN * 64];
  const int bn = blockIdx.x * TN;
  const int bm = blockIdx.y * 128;
  const int tid  = threadIdx.x;
  const int wid  = tid >> 6;
  const int lane = tid & 63;
  const int wm = (wid >> 1) * 64;
  const int wn = (wid & 1) * (TN / 2);

  f32x4 acc[4][NB] = {};

  for (int k0 = 0; k0 < Kp; k0 += 64) {
    #pragma unroll
    for (int i = 0; i < 4; ++i) {
      int s = (i * 4 + wid) * 64 + lane;
      int row = s >> 3, cs = (s & 7) << 3;
      const short* src = A + (size_t)(bm + row) * lda + k0 + cs;
      __builtin_amdgcn_global_load_lds(
          (const __attribute__((address_space(1))) void*)src,
          (__attribute__((address_space(3))) void*)(As + (size_t)(i * 4 + wid) * 64 * 8),
          16, 0, 0);
    }
    #pragma unroll
    for (int i = 0; i < TN / 32; ++i) {
      int s = (i * 4 + wid) * 64 + lane;
      int n = s >> 3, cs = (s & 7) << 3;
      const short* src = Wt + (size_t)(bn + n) * Kp + k0 + cs;
      __builtin_amdgcn_global_load_lds(
          (const __attribute__((address_space(1))) void*)src,
          (__attribute__((address_space(3))) void*)(Bs + (size_t)(i * 4 + wid) * 64 * 8),
          16, 0, 0);
    }
    __syncthreads();

    #pragma unroll
    for (int ks = 0; ks < 2; ++ks) {
      const int kof = ks * 32 + (lane >> 4) * 8;
      bf16x8 a[4], b[NB];
      #pragma unroll
      for (int mi = 0; mi < 4; ++mi)
        a[mi] = *(const bf16x8*)&As[(wm + mi * 16 + (lane & 15)) * 64 + kof];
      #pragma unroll
      for (int ni = 0; ni < NB; ++ni)
        b[ni] = *(const bf16x8*)&Bs[(wn + ni * 16 + (lane & 15)) * 64 + kof];
      #pragma unroll
      for (int mi = 0; mi < 4; ++mi)
        #pragma unroll
        for (int ni = 0; ni < NB; ++ni)
          acc[mi][ni] = __builtin_amdgcn_mfma_f32_16x16x32_bf16(a[mi], b[ni], acc[mi][ni], 0, 0, 0);
    }
    __syncthreads();
  }

  const int col0 = bn + wn + (lane & 15);
  const int row0 = bm + wm + (lane >> 4) * 4;
  #pragma unroll
  for (int ni = 0; ni < NB; ++ni) {
    int col = col0 + ni * 16;
    float bv = (col < nbias) ? bias[col] : 0.f;
    float colsum = 0.f;
    #pragma unroll
    for (int mi = 0; mi < 4; ++mi) {
      #pragma unroll
      for (int j = 0; j < 4; ++j) {
        int row = row0 + mi * 16 + j;
        float v = acc[mi][ni][j] + bv;
        if (EPI == 0) {
          if (RELU) v = v > 0.f ? v : 0.2f * v;
          if (OUTBF16) ((short*)Cout)[(size_t)row * Np + col] = f2bf(v);
          else         ((float*)Cout)[(size_t)row * Np + col] = v;
        } else if (EPI == 1) {
          if (col < 32) {
            aux[(size_t)row * 64 + 32 + col] = f2bf(v);   // vloss -> clvl cols 32..63
          } else if (col < 160) {
            ((short*)Cout)[(size_t)row * Np + col] = f2bf(v);
            colsum += v;
          }
        } else {  // EPI == 2
          ((short*)Cout)[(size_t)row * Np + col] = f2bf(v);
          colsum += v;
        }
      }
    }
    if ((EPI == 1 && col >= 32 && col < 160) || EPI == 2) {
      colsum += __shfl_xor(colsum, 16);
      colsum += __shfl_xor(colsum, 32);
      if ((lane >> 4) == 0) {
        int midx = (EPI == 1) ? (col - 32) : col;
        atomicAdd(&meanbuf[(size_t)(bm >> gshift) * 128 + midx], colsum * inv_cnt);
      }
    }
  }
}

// ---------------- merged: pairnorm_c (bf16 state in xcmb) AND gather -> xugb ----------------
__global__ __launch_bounds__(256) void pnc_gather_kernel(
    const short* __restrict__ CDb, const float* __restrict__ cmean,
    short* __restrict__ xcmb,
    const float* __restrict__ Q, const int* __restrict__ cso, const int* __restrict__ cse,
    const short* __restrict__ clvl, short* __restrict__ xugb) {
  int b = blockIdx.x;
  if (b < NCLS / 4) {
    int wid = threadIdx.x >> 6;
    int lane = threadIdx.x & 63;
    int row = b * 4 + wid;
    int g = row >> 10;
    const short* xp = CDb + (size_t)row * 192 + 32;
    float y0 = bf2f(xp[lane])      - cmean[g * 128 + lane];
    float y1 = bf2f(xp[lane + 64]) - cmean[g * 128 + lane + 64];
    float ss = y0 * y0 + y1 * y1;
    #pragma unroll
    for (int o = 32; o > 0; o >>= 1) ss += __shfl_xor(ss, o);
    float inv = rsqrtf(ss * (1.f / 128.f) + 1e-6f);
    short* sp = xcmb + (size_t)row * 192;
    float s0 = y0 * inv * 0.25f + 0.1f * bf2f(sp[lane]);
    float s1 = y1 * inv * 0.25f + 0.1f * bf2f(sp[lane + 64]);
    sp[lane]      = f2bf(s0);
    sp[lane + 64] = f2bf(s1);
  } else {
    int t = (b - NCLS / 4) * 256 + threadIdx.x;
    int v = t >> 5, m = t & 31;
    float q = Q[(size_t)v * 32 + m];
    float sig = 1.f / (1.f + expf(-q));
    float vgs = 0.f, lps = 0.f, lns = 0.f;
    int e0 = cso[v], e1 = cso[v + 1];
    for (int e = e0; e < e1; ++e) {
      int ent = cse[e];
      int c = ent >> 1;
      bool pos = ent & 1;
      float clc = bf2f(clvl[(size_t)c * 64 + m]);
      float vl  = bf2f(clvl[(size_t)c * 64 + 32 + m]);
      vgs -= clc * (sig - (pos ? 0.f : 1.f));
      if (pos) lps += vl; else lns += vl;
    }
    short* xp = xugb + (size_t)v * 256 + 128;
    xp[m]      = f2bf(vgs);
    xp[32 + m] = f2bf(lps);
    xp[64 + m] = f2bf(lns);
  }
}

// ---------------- pair_norm + state update (bf16 state in xugb) ----------------
__global__ __launch_bounds__(256) void pairnorm_update_kernel(
    const short* __restrict__ CDb, const float* __restrict__ vmean,
    short* __restrict__ xugb) {
  int wid = threadIdx.x >> 6;
  int lane = threadIdx.x & 63;
  int row = blockIdx.x * 4 + wid;
  int g = row >> 9;   // 512 rows per graph
  float y0 = bf2f(CDb[(size_t)row * 128 + lane])      - vmean[g * 128 + lane];
  float y1 = bf2f(CDb[(size_t)row * 128 + lane + 64]) - vmean[g * 128 + lane + 64];
  float ss = y0 * y0 + y1 * y1;
  #pragma unroll
  for (int o = 32; o > 0; o >>= 1) ss += __shfl_xor(ss, o);
  float inv = rsqrtf(ss * (1.f / 128.f) + 1e-6f);
  short* sp = xugb + (size_t)row * 256;
  float s0 = y0 * inv * 0.25f + 0.1f * bf2f(sp[lane]);
  float s1 = y1 * inv * 0.25f + 0.1f * bf2f(sp[lane + 64]);
  sp[lane]      = f2bf(s0);
  sp[lane + 64] = f2bf(s1);
}

// ---------------- fused vo MLP: xugb[:, :128] -> logits f32 ----------------
__global__ __launch_bounds__(256) void fused_vo_kernel(
    const short* __restrict__ xugb,
    const short* __restrict__ w0, const short* __restrict__ w1,
    const float* __restrict__ b0, const float* __restrict__ b1,
    const float* __restrict__ w2, const float* __restrict__ b2,
    float* __restrict__ logits) {
  __shared__ short A[64 * 128];
  __shared__ short H1[4][16 * 128];
  __shared__ short H2[4][16 * 128];
  const int wid = threadIdx.x >> 6, lane = threadIdx.x & 63;
  const int rbase = blockIdx.x * 64 + wid * 16;
  #pragma unroll
  for (int i = 0; i < 4; ++i) {
    int s = i * 64 + lane;
    int row = s >> 4, c8 = s & 15;
    *(bf16x8*)&A[(wid * 16 + row) * 128 + c8 * 8] =
        *(const bf16x8*)&xugb[(size_t)(rbase + row) * 256 + c8 * 8];
  }
  const int kof = (lane >> 4) * 8;
  const int l15 = lane & 15;
  f32x4 acc[8] = {};
  #pragma unroll
  for (int ks = 0; ks < 4; ++ks) {
    bf16x8 a = *(const bf16x8*)&A[(wid * 16 + l15) * 128 + ks * 32 + kof];
    #pragma unroll
    for (int ni = 0; ni < 8; ++ni) {
      bf16x8 b = *(const bf16x8*)&w0[(ni * 16 + l15) * 128 + ks * 32 + kof];
      acc[ni] = __builtin_amdgcn_mfma_f32_16x16x32_bf16(a, b, acc[ni], 0, 0, 0);
    }
  }
  #pragma unroll
  for (int ni = 0; ni < 8; ++ni) {
    int col = ni * 16 + l15;
    float bb = b0[col];
    #pragma unroll
    for (int j = 0; j < 4; ++j) {
      float v = acc[ni][j] + bb; v = v > 0.f ? v : 0.2f * v;
      H1[wid][((lane >> 4) * 4 + j) * 128 + col] = f2bf(v);
    }
  }
  f32x4 acc2[8] = {};
  #pragma unroll
  for (int ks = 0; ks < 4; ++ks) {
    bf16x8 a = *(const bf16x8*)&H1[wid][l15 * 128 + ks * 32 + kof];
    #pragma unroll
    for (int ni = 0; ni < 8; ++ni) {
      bf16x8 b = *(const bf16x8*)&w1[(ni * 16 + l15) * 128 + ks * 32 + kof];
      acc2[ni] = __builtin_amdgcn_mfma_f32_16x16x32_bf16(a, b, acc2[ni], 0, 0, 0);
    }
  }
  #pragma unroll
  for (int ni = 0; ni < 8; ++ni) {
    int col = ni * 16 + l15;
    float bb = b1[col];
    #pragma unroll
    for (int j = 0; j < 4; ++j) {
      float v = acc2[ni][j] + bb; v = v > 0.f ? v : 0.2f * v;
      H2[wid][((lane >> 4) * 4 + j) * 128 + col] = f2bf(v);
    }
  }
  {
    int row = lane >> 2, q = lane & 3;
    float s = 0.f;
    #pragma unroll
    for (int jj = 0; jj < 4; ++jj) {
      bf16x8 h = *(const bf16x8*)&H2[wid][row * 128 + q * 32 + jj * 8];
      #pragma unroll
      for (int e = 0; e < 8; ++e) s += bf2f(h[e]) * w2[q * 32 + jj * 8 + e];
    }
    s += __shfl_xor(s, 1);
    s += __shfl_xor(s, 2);
    if (q == 0) logits[rbase + row] = s + b2[0];
  }
}

// ---------------- per-clause loss + per-graph sqrt reduce ----------------
__global__ __launch_bounds__(1024) void fused_loss_kernel(
    const float* __restrict__ logits, const int* __restrict__ lit_var,
    const int* __restrict__ lit_sign, float* __restrict__ loss) {
  __shared__ float lg[512];
  __shared__ float red[16];
  int g = blockIdx.x, tid = threadIdx.x;
  if (tid < 512) lg[tid] = logits[(size_t)g * 512 + tid];
  __syncthreads();
  int c = g * 1024 + tid;
  float s = 0.f;
  #pragma unroll
  for (int i = 0; i < 3; ++i) {
    int l = 3 * c + i;
    float sg = (float)lit_sign[l];
    s += softplus_f(lg[lit_var[l] - g * 512] * sg);
  }
  float vv = expf(-s);
  float pcv = vv * (-logf(1.f - vv + 1e-8f));
  #pragma unroll
  for (int o = 32; o > 0; o >>= 1) pcv += __shfl_xor(pcv, o);
  if ((tid & 63) == 0) red[tid >> 6] = pcv;
  __syncthreads();
  if (tid < 16) {
    float x = red[tid];
    #pragma unroll
    for (int o = 8; o > 0; o >>= 1) x += __shfl_xor(x, o);
    if (tid == 0) atomicAdd(loss, sqrtf(x + 1e-6f));
  }
}

__global__ void finalize_kernel(const float* __restrict__ loss_acc, float* __restrict__ out) {
  out[0] = loss_acc[0] * 0.25f;
}

// =======================================================================
extern "C" void kernel_launch(void* const* d_in, const int* in_sizes, int n_in,
                              void* d_out, int out_size, void* d_ws, size_t ws_size,
                              hipStream_t stream) {
  const int* lit_var    = (const int*)d_in[0];
  const int* lit_sign   = (const int*)d_in[1];
  const int* lit_clause = (const int*)d_in[2];
  const float* noise    = (const float*)d_in[5];
  const float* vq_w0 = (const float*)d_in[6];   const float* vq_b0 = (const float*)d_in[7];
  const float* vq_w1 = (const float*)d_in[8];   const float* vq_b1 = (const float*)d_in[9];
  const float* vq_w2 = (const float*)d_in[10];  const float* vq_b2 = (const float*)d_in[11];
  const float* cm_w0 = (const float*)d_in[12];  const float* cm_b0 = (const float*)d_in[13];
  const float* cm_w1 = (const float*)d_in[14];  const float* cm_b1 = (const float*)d_in[15];
  const float* cm_w2 = (const float*)d_in[16];  const float* cm_b2 = (const float*)d_in[17];
  const float* ug_w0 = (const float*)d_in[18];  const float* ug_b0 = (const float*)d_in[19];
  const float* ug_w1 = (const float*)d_in[20];  const float* ug_b1 = (const float*)d_in[21];
  const float* ug_w2 = (const float*)d_in[22];  const float* ug_b2 = (const float*)d_in[23];
  const float* vo_w0 = (const float*)d_in[24];  const float* vo_b0 = (const float*)d_in[25];
  const float* vo_w1 = (const float*)d_in[26];  const float* vo_b1 = (const float*)d_in[27];
  const float* vo_w2 = (const float*)d_in[28];  const float* vo_b2 = (const float*)d_in[29];

  float* ws = (float*)d_ws;
  short* clvl  = (short*)(ws + OFF_CLVL);
  short* xcmb  = (short*)(ws + OFF_XCMB);
  short* xugb  = (short*)(ws + OFF_XUGB);
  short* bufA  = (short*)(ws + OFF_ABUF);
  short* bufB  = (short*)(ws + OFF_BBUF);
  short* CDb   = (short*)(ws + OFF_CD);
  float* Q     = ws + OFF_Q;
  float* cmean = ws + OFF_CMEAN;
  float* vmean = ws + OFF_VMEAN;
  float* loss  = ws + OFF_LOSS;
  int*   cso   = (int*)(ws + OFF_CSO);
  int*   cse   = (int*)(ws + OFF_CSE);
  int*   csc   = (int*)(ws + OFF_CSC);
  short* wt    = (short*)(ws + OFF_WT);
  float* logits = (float*)d_out;
  float* loss_out = (float*)d_out + NVARS;

  convert_all_kernel<<<1984, 256, 0, stream>>>(cm_w0, cm_w1, cm_w2, ug_w0, ug_w1, ug_w2,
                                               vo_w0, vo_w1, vq_w0, vq_w1, vq_w2, wt);
  init_state_kernel<<<30784, 256, 0, stream>>>(xugb, xcmb, loss, csc);
  csr_count_kernel<<<NLITS / 256, 256, 0, stream>>>(lit_var, csc);
  csr_scan_kernel<<<1, 1024, 0, stream>>>(csc, cso, csc);
  csr_fill_kernel<<<NLITS / 256, 256, 0, stream>>>(lit_var, lit_sign, lit_clause, csc, cse);

  for (int r = 0; r < NROUNDS; ++r) {
    const float* noise_r = noise + (size_t)r * NVARS * 4;

    // vq MLP -> Q
    fused_vq_kernel<<<NVARS / 64, 256, 0, stream>>>(
        xugb, noise_r, wt + WT_VQ0, wt + WT_VQ1, wt + WT_VQ2, vq_b0, vq_b1, vq_b2, Q);

    // clause_val -> clvl + xcmb tail; zero means
    fused_clause_kernel<<<NCLS * 32 / 256, 256, 0, stream>>>(Q, lit_var, lit_sign, xcmb, clvl, cmean);

    // cm MLP
    gemm_mfma_kernel<128, true, true, 0><<<dim3(3, NCLS / 128), 256, 0, stream>>>(
        xcmb, 192, wt + WT_CM0, cm_b0, 384, bufA, 384, 192, nullptr, nullptr, 0.f, 0);
    gemm_mfma_kernel<128, true, true, 0><<<dim3(3, NCLS / 128), 256, 0, stream>>>(
        bufA, 384, wt + WT_CM1, cm_b1, 384, bufB, 384, 384, nullptr, nullptr, 0.f, 0);
    gemm_mfma_kernel<64, false, false, 1><<<dim3(3, NCLS / 128), 256, 0, stream>>>(
        bufB, 384, wt + WT_CM2, cm_b2, 160, CDb, 192, 384, clvl, cmean, 1.f / 1024.f, 10);

    // pairnorm_c (bf16 state) + gather (vg/lp/ln -> xugb cols 128..223)
    pnc_gather_kernel<<<NCLS / 4 + NVARS * 32 / 256, 256, 0, stream>>>(
        CDb, cmean, xcmb, Q, cso, cse, clvl, xugb);

    // ug MLP
    gemm_mfma_kernel<128, true, true, 0><<<dim3(2, NVARS / 128), 256, 0, stream>>>(
        xugb, 256, wt + WT_UG0, ug_b0, 256, bufA, 256, 256, nullptr, nullptr, 0.f, 0);
    gemm_mfma_kernel<128, true, true, 0><<<dim3(2, NVARS / 128), 256, 0, stream>>>(
        bufA, 256, wt + WT_UG1, ug_b1, 256, bufB, 256, 256, nullptr, nullptr, 0.f, 0);
    gemm_mfma_kernel<64, false, false, 2><<<dim3(2, NVARS / 128), 256, 0, stream>>>(
        bufB, 256, wt + WT_UG2, ug_b2, 128, CDb, 128, 256, nullptr, vmean, 1.f / 512.f, 9);

    // variables pair_norm update (bf16 state in xugb)
    pairnorm_update_kernel<<<NVARS / 4, 256, 0, stream>>>(CDb, vmean, xugb);

    // vo MLP -> logits
    fused_vo_kernel<<<NVARS / 64, 256, 0, stream>>>(
        xugb, wt + WT_VO0, wt + WT_VO1, vo_b0, vo_b1, vo_w2, vo_b2, logits);

    // loss
    fused_loss_kernel<<<NG, 1024, 0, stream>>>(logits, lit_var, lit_sign, loss);
  }

  finalize_kernel<<<1, 1, 0, stream>>>(loss, loss_out);
}

// Round 12
// 653.045 us; speedup vs baseline: 1.1578x; 1.0019x over previous
//
#include <hip/hip_runtime.h>
#include <hip/hip_bf16.h>
#include <math.h>

#define NG     32
#define NVARS  16384
#define NCLS   32768
#define NLITS  98304
#define NROUNDS 4

typedef __attribute__((ext_vector_type(8))) short bf16x8;
typedef __attribute__((ext_vector_type(4))) float f32x4;

// ---------------- workspace layout (float units) ----------------
#define OFF_CLVL   ((size_t)0)            // bf16 32768x64: cols 0..31 = cl, 32..63 = vloss
#define OFF_XCMB   ((size_t)6291456)      // bf16 32768x192 (cols 0..127 = clause state)
#define OFF_XUGB   ((size_t)9437184)      // bf16 16384x256 (cols 0..127 = variable state)
#define OFF_ABUF   ((size_t)11534336)     // bf16 32768x384
#define OFF_BBUF   ((size_t)17825792)     // bf16 32768x384
#define OFF_CD     ((size_t)24117248)     // bf16 32768x192 (also UO 16384x128 bf16)
#define OFF_Q      ((size_t)30408704)     // f32 16384x32
#define OFF_CMEAN  ((size_t)33030144)     // f32 32x128 (cmean+vmean contiguous)
#define OFF_VMEAN  ((size_t)33034240)     // f32 32x128
#define OFF_LOSS   ((size_t)33038336)     // f32 1
#define OFF_CSO    ((size_t)33038340)     // int 16385
#define OFF_CSE    ((size_t)33054725)     // int 98304 ((clause<<1)|pos)
#define OFF_CSC    ((size_t)33153029)     // int 16384
#define OFF_WT     ((size_t)33169416)     // bf16 pool 507904 elems

#define WT_CM0  ((size_t)0)       // [384][192]
#define WT_CM1  ((size_t)73728)   // [384][384]
#define WT_CM2  ((size_t)221184)  // [192][384]
#define WT_UG0  ((size_t)294912)  // [256][256]
#define WT_UG1  ((size_t)360448)  // [256][256]
#define WT_UG2  ((size_t)425984)  // [128][256]
#define WT_VO0  ((size_t)458752)  // [128][128]
#define WT_VO1  ((size_t)475136)  // [128][128]
#define WT_VQ0  ((size_t)491520)  // [64][160]
#define WT_VQ1  ((size_t)501760)  // [64][64]
#define WT_VQ2  ((size_t)505856)  // [32][64]

__device__ __forceinline__ float softplus_f(float x) {
  return fmaxf(x, 0.f) + log1pf(expf(-fabsf(x)));
}
__device__ __forceinline__ short f2bf(float x) {
  __hip_bfloat16 h = __float2bfloat16(x);
  return *reinterpret_cast<short*>(&h);
}
__device__ __forceinline__ float bf2f(short s) {
  __hip_bfloat16 h = *reinterpret_cast<__hip_bfloat16*>(&s);
  return __bfloat162float(h);
}

// ---------------- init: bf16 states + constant pads + loss=0 + csr cnt=0 ----------------
__global__ void init_state_kernel(short* __restrict__ xugb, short* __restrict__ xcmb,
                                  float* __restrict__ loss, int* __restrict__ cnt) {
  int t = blockIdx.x * blockDim.x + threadIdx.x;
  if (t == 0) *loss = 0.f;
  const int main_total = (NVARS + NCLS) * 128;
  if (t < main_total) {
    int row = t >> 7, m = t & 127;
    const float base = 2.82842712474619f; // sqrt(128)*0.25
    float val = ((m == 0) ? (1.f - 1.f / 128.f) : (-1.f / 128.f)) * base;
    if (row < NVARS) xugb[(size_t)row * 256 + m] = f2bf(val);
    else             xcmb[(size_t)(row - NVARS) * 192 + m] = f2bf(val);
    return;
  }
  int t2 = t - main_total;
  if (t2 < NVARS * 32) {           // xugb cols 224..255 = 0 forever
    int row = t2 >> 5, j = t2 & 31;
    xugb[(size_t)row * 256 + 224 + j] = 0;
    return;
  }
  int t3 = t2 - NVARS * 32;
  if (t3 < NCLS * 32) {            // xcmb cols 160..191 = 0 forever
    int row = t3 >> 5, j = t3 & 31;
    xcmb[(size_t)row * 192 + 160 + j] = 0;
    return;
  }
  int t4 = t3 - NCLS * 32;
  if (t4 < NVARS) cnt[t4] = 0;
}

// ---------------- CSR build ----------------
__global__ void csr_count_kernel(const int* __restrict__ lit_var, int* __restrict__ cnt) {
  int l = blockIdx.x * blockDim.x + threadIdx.x;
  if (l >= NLITS) return;
  atomicAdd(&cnt[lit_var[l]], 1);
}

__global__ __launch_bounds__(1024) void csr_scan_kernel(const int* __restrict__ cnt,
                                                        int* __restrict__ cso,
                                                        int* __restrict__ cur) {
  __shared__ int part[1024];
  int t = threadIdx.x;
  int base = t * 16;
  int local[16];
  int s = 0;
  #pragma unroll
  for (int i = 0; i < 16; ++i) { local[i] = cnt[base + i]; s += local[i]; }
  part[t] = s;
  __syncthreads();
  for (int off = 1; off < 1024; off <<= 1) {
    int v = (t >= off) ? part[t - off] : 0;
    __syncthreads();
    part[t] += v;
    __syncthreads();
  }
  int run = part[t] - s;
  #pragma unroll
  for (int i = 0; i < 16; ++i) {
    cso[base + i] = run;
    cur[base + i] = run;
    run += local[i];
  }
  if (t == 1023) cso[NVARS] = run;
}

__global__ void csr_fill_kernel(const int* __restrict__ lit_var, const int* __restrict__ lit_sign,
                                const int* __restrict__ lit_clause,
                                int* __restrict__ cur, int* __restrict__ cse) {
  int l = blockIdx.x * blockDim.x + threadIdx.x;
  if (l >= NLITS) return;
  int v = lit_var[l];
  int pos = atomicAdd(&cur[v], 1);
  cse[pos] = (lit_clause[l] << 1) | (lit_sign[l] > 0 ? 1 : 0);
}

// ---------------- weight convert ----------------
__global__ void convert_all_kernel(
    const float* __restrict__ cm_w0, const float* __restrict__ cm_w1, const float* __restrict__ cm_w2,
    const float* __restrict__ ug_w0, const float* __restrict__ ug_w1, const float* __restrict__ ug_w2,
    const float* __restrict__ vo_w0, const float* __restrict__ vo_w1,
    const float* __restrict__ vq_w0, const float* __restrict__ vq_w1, const float* __restrict__ vq_w2,
    short* __restrict__ wt) {
  int t = blockIdx.x * blockDim.x + threadIdx.x;
  const float* W; int K, N, Kp; size_t base; int idx;
  if      (t < 73728)  { W = cm_w0; K = 160; N = 384; Kp = 192; base = WT_CM0; idx = t; }
  else if (t < 221184) { W = cm_w1; K = 384; N = 384; Kp = 384; base = WT_CM1; idx = t - 73728; }
  else if (t < 294912) { W = cm_w2; K = 384; N = 160; Kp = 384; base = WT_CM2; idx = t - 221184; }
  else if (t < 360448) { W = ug_w0; K = 224; N = 256; Kp = 256; base = WT_UG0; idx = t - 294912; }
  else if (t < 425984) { W = ug_w1; K = 256; N = 256; Kp = 256; base = WT_UG1; idx = t - 360448; }
  else if (t < 458752) { W = ug_w2; K = 256; N = 128; Kp = 256; base = WT_UG2; idx = t - 425984; }
  else if (t < 475136) { W = vo_w0; K = 128; N = 128; Kp = 128; base = WT_VO0; idx = t - 458752; }
  else if (t < 491520) { W = vo_w1; K = 128; N = 128; Kp = 128; base = WT_VO1; idx = t - 475136; }
  else if (t < 501760) { W = vq_w0; K = 132; N = 64;  Kp = 160; base = WT_VQ0; idx = t - 491520; }
  else if (t < 505856) { W = vq_w1; K = 64;  N = 64;  Kp = 64;  base = WT_VQ1; idx = t - 501760; }
  else if (t < 507904) { W = vq_w2; K = 64;  N = 32;  Kp = 64;  base = WT_VQ2; idx = t - 505856; }
  else return;
  int n = idx / Kp, k = idx - n * Kp;
  float v = (k < K && n < N) ? W[(size_t)k * N + n] : 0.f;
  wt[base + idx] = f2bf(v);
}

// ---------------- fused vq MLP (+ optional absorbed loss of previous round) ----------------
__global__ __launch_bounds__(256) void fused_vq_kernel(
    const short* __restrict__ xugb, const float* __restrict__ noise,
    const short* __restrict__ w0, const short* __restrict__ w1, const short* __restrict__ w2,
    const float* __restrict__ b0, const float* __restrict__ b1, const float* __restrict__ b2,
    float* __restrict__ Q,
    const float* __restrict__ logits_in, const int* __restrict__ lit_var,
    const int* __restrict__ lit_sign, float* __restrict__ loss, int do_loss) {
  __shared__ short A[64 * 160];
  __shared__ short H1[4][16 * 64];
  __shared__ short H2[4][16 * 64];
  __shared__ float lred[4];
  const int wid = threadIdx.x >> 6, lane = threadIdx.x & 63;
  // absorbed loss of previous round: blocks 0..31 each reduce one graph.
  // Runs before the MLP staging so global loads overlap; adds ~3us to 32/256 blocks.
  if (do_loss && blockIdx.x < NG) {
    int g = blockIdx.x;
    float part = 0.f;
    #pragma unroll
    for (int k = 0; k < 4; ++k) {
      int c = g * 1024 + k * 256 + threadIdx.x;
      int l0 = 3 * c;
      float s = 0.f;
      #pragma unroll
      for (int i = 0; i < 3; ++i) {
        int l = l0 + i;
        float sg = (float)lit_sign[l];
        s += softplus_f(logits_in[lit_var[l]] * sg);
      }
      float vv = expf(-s);
      part += vv * (-logf(1.f - vv + 1e-8f));
    }
    #pragma unroll
    for (int o = 32; o > 0; o >>= 1) part += __shfl_xor(part, o);
    if (lane == 0) lred[wid] = part;
    __syncthreads();
    if (threadIdx.x == 0)
      atomicAdd(loss, sqrtf(lred[0] + lred[1] + lred[2] + lred[3] + 1e-6f));
  }
  const int rbase = blockIdx.x * 64 + wid * 16;
  #pragma unroll
  for (int i = 0; i < 4; ++i) {
    int s = i * 64 + lane;
    int row = s >> 4, c8 = s & 15;
    *(bf16x8*)&A[(wid * 16 + row) * 160 + c8 * 8] =
        *(const bf16x8*)&xugb[(size_t)(rbase + row) * 256 + c8 * 8];
  }
  {
    int row = lane >> 2, seg = lane & 3;
    bf16x8 z = {0, 0, 0, 0, 0, 0, 0, 0};
    if (seg == 0) {
      float4 nz = *(const float4*)&noise[(size_t)(rbase + row) * 4];
      z[0] = f2bf(nz.x); z[1] = f2bf(nz.y); z[2] = f2bf(nz.z); z[3] = f2bf(nz.w);
    }
    *(bf16x8*)&A[(wid * 16 + row) * 160 + 128 + seg * 8] = z;
  }
  const int kof = (lane >> 4) * 8;
  const int l15 = lane & 15;
  f32x4 acc[4] = {};
  #pragma unroll
  for (int ks = 0; ks < 5; ++ks) {
    bf16x8 a = *(const bf16x8*)&A[(wid * 16 + l15) * 160 + ks * 32 + kof];
    #pragma unroll
    for (int ni = 0; ni < 4; ++ni) {
      bf16x8 b = *(const bf16x8*)&w0[(ni * 16 + l15) * 160 + ks * 32 + kof];
      acc[ni] = __builtin_amdgcn_mfma_f32_16x16x32_bf16(a, b, acc[ni], 0, 0, 0);
    }
  }
  #pragma unroll
  for (int ni = 0; ni < 4; ++ni) {
    int col = ni * 16 + l15;
    float bb = b0[col];
    #pragma unroll
    for (int j = 0; j < 4; ++j) {
      float v = acc[ni][j] + bb; v = v > 0.f ? v : 0.2f * v;
      H1[wid][((lane >> 4) * 4 + j) * 64 + col] = f2bf(v);
    }
  }
  f32x4 acc2[4] = {};
  #pragma unroll
  for (int ks = 0; ks < 2; ++ks) {
    bf16x8 a = *(const bf16x8*)&H1[wid][l15 * 64 + ks * 32 + kof];
    #pragma unroll
    for (int ni = 0; ni < 4; ++ni) {
      bf16x8 b = *(const bf16x8*)&w1[(ni * 16 + l15) * 64 + ks * 32 + kof];
      acc2[ni] = __builtin_amdgcn_mfma_f32_16x16x32_bf16(a, b, acc2[ni], 0, 0, 0);
    }
  }
  #pragma unroll
  for (int ni = 0; ni < 4; ++ni) {
    int col = ni * 16 + l15;
    float bb = b1[col];
    #pragma unroll
    for (int j = 0; j < 4; ++j) {
      float v = acc2[ni][j] + bb; v = v > 0.f ? v : 0.2f * v;
      H2[wid][((lane >> 4) * 4 + j) * 64 + col] = f2bf(v);
    }
  }
  f32x4 acc3[2] = {};
  #pragma unroll
  for (int ks = 0; ks < 2; ++ks) {
    bf16x8 a = *(const bf16x8*)&H2[wid][l15 * 64 + ks * 32 + kof];
    #pragma unroll
    for (int ni = 0; ni < 2; ++ni) {
      bf16x8 b = *(const bf16x8*)&w2[(ni * 16 + l15) * 64 + ks * 32 + kof];
      acc3[ni] = __builtin_amdgcn_mfma_f32_16x16x32_bf16(a, b, acc3[ni], 0, 0, 0);
    }
  }
  #pragma unroll
  for (int ni = 0; ni < 2; ++ni) {
    int col = ni * 16 + l15;
    float bb = b2[col];
    #pragma unroll
    for (int j = 0; j < 4; ++j)
      Q[(size_t)(rbase + (lane >> 4) * 4 + j) * 32 + col] = acc3[ni][j] + bb;
  }
}

// ---------------- clause_val -> clvl[:, :32] + xcmb tail; zero cmean/vmean ----------------
__global__ void fused_clause_kernel(const float* __restrict__ Q, const int* __restrict__ lit_var,
                                    const int* __restrict__ lit_sign,
                                    short* __restrict__ xcmb, short* __restrict__ clvl,
                                    float* __restrict__ meanz) {
  int t = blockIdx.x * blockDim.x + threadIdx.x;
  if (t < 2 * 32 * 128) meanz[t] = 0.f;
  if (t >= NCLS * 32) return;
  int c = t >> 5, m = t & 31;
  int l0 = 3 * c;
  int v0 = lit_var[l0], v1 = lit_var[l0 + 1], v2 = lit_var[l0 + 2];
  int s0 = lit_sign[l0], s1 = lit_sign[l0 + 1], s2 = lit_sign[l0 + 2];
  float q0 = Q[(size_t)v0 * 32 + m];
  float q1 = Q[(size_t)v1 * 32 + m];
  float q2 = Q[(size_t)v2 * 32 + m];
  float sp = softplus_f(q0 * (float)s0) + softplus_f(q1 * (float)s1) + softplus_f(q2 * (float)s2);
  float cl = expf(-sp);
  short clb = f2bf(cl);
  xcmb[(size_t)c * 192 + 128 + m] = clb;
  clvl[(size_t)c * 64 + m] = clb;
}

// ---------------- bf16 MFMA GEMM template ----------------
// EPI 0: plain. EPI 1: cm2 (vloss bf16 -> clvl cols 32..63; CD bf16 cols 32..159 + cmean).
// EPI 2: ug2 (bf16 out all cols + vmean).
template<int TN, bool RELU, bool OUTBF16, int EPI>
__global__ __launch_bounds__(256) void gemm_mfma_kernel(
    const short* __restrict__ A, int lda,
    const short* __restrict__ Wt,
    const float* __restrict__ bias, int nbias,
    void* __restrict__ Cout, int Np, int Kp,
    short* __restrict__ aux,
    float* __restrict__ meanbuf, float inv_cnt, int gshift) {
  constexpr int NB = TN / 32;
  __shared__ short As[128 * 64];
  __shared__ short Bs[TN * 64];
  const int bn = blockIdx.x * TN;
  const int bm = blockIdx.y * 128;
  const int tid  = threadIdx.x;
  const int wid  = tid >> 6;
  const int lane = tid & 63;
  const int wm = (wid >> 1) * 64;
  const int wn = (wid & 1) * (TN / 2);

  f32x4 acc[4][NB] = {};

  for (int k0 = 0; k0 < Kp; k0 += 64) {
    #pragma unroll
    for (int i = 0; i < 4; ++i) {
      int s = (i * 4 + wid) * 64 + lane;
      int row = s >> 3, cs = (s & 7) << 3;
      const short* src = A + (size_t)(bm + row) * lda + k0 + cs;
      __builtin_amdgcn_global_load_lds(
          (const __attribute__((address_space(1))) void*)src,
          (__attribute__((address_space(3))) void*)(As + (size_t)(i * 4 + wid) * 64 * 8),
          16, 0, 0);
    }
    #pragma unroll
    for (int i = 0; i < TN / 32; ++i) {
      int s = (i * 4 + wid) * 64 + lane;
      int n = s >> 3, cs = (s & 7) << 3;
      const short* src = Wt + (size_t)(bn + n) * Kp + k0 + cs;
      __builtin_amdgcn_global_load_lds(
          (const __attribute__((address_space(1))) void*)src,
          (__attribute__((address_space(3))) void*)(Bs + (size_t)(i * 4 + wid) * 64 * 8),
          16, 0, 0);
    }
    __syncthreads();

    #pragma unroll
    for (int ks = 0; ks < 2; ++ks) {
      const int kof = ks * 32 + (lane >> 4) * 8;
      bf16x8 a[4], b[NB];
      #pragma unroll
      for (int mi = 0; mi < 4; ++mi)
        a[mi] = *(const bf16x8*)&As[(wm + mi * 16 + (lane & 15)) * 64 + kof];
      #pragma unroll
      for (int ni = 0; ni < NB; ++ni)
        b[ni] = *(const bf16x8*)&Bs[(wn + ni * 16 + (lane & 15)) * 64 + kof];
      #pragma unroll
      for (int mi = 0; mi < 4; ++mi)
        #pragma unroll
        for (int ni = 0; ni < NB; ++ni)
          acc[mi][ni] = __builtin_amdgcn_mfma_f32_16x16x32_bf16(a[mi], b[ni], acc[mi][ni], 0, 0, 0);
    }
    __syncthreads();
  }

  const int col0 = bn + wn + (lane & 15);
  const int row0 = bm + wm + (lane >> 4) * 4;
  #pragma unroll
  for (int ni = 0; ni < NB; ++ni) {
    int col = col0 + ni * 16;
    float bv = (col < nbias) ? bias[col] : 0.f;
    float colsum = 0.f;
    #pragma unroll
    for (int mi = 0; mi < 4; ++mi) {
      #pragma unroll
      for (int j = 0; j < 4; ++j) {
        int row = row0 + mi * 16 + j;
        float v = acc[mi][ni][j] + bv;
        if (EPI == 0) {
          if (RELU) v = v > 0.f ? v : 0.2f * v;
          if (OUTBF16) ((short*)Cout)[(size_t)row * Np + col] = f2bf(v);
          else         ((float*)Cout)[(size_t)row * Np + col] = v;
        } else if (EPI == 1) {
          if (col < 32) {
            aux[(size_t)row * 64 + 32 + col] = f2bf(v);   // vloss -> clvl cols 32..63
          } else if (col < 160) {
            ((short*)Cout)[(size_t)row * Np + col] = f2bf(v);
            colsum += v;
          }
        } else {  // EPI == 2
          ((short*)Cout)[(size_t)row * Np + col] = f2bf(v);
          colsum += v;
        }
      }
    }
    if ((EPI == 1 && col >= 32 && col < 160) || EPI == 2) {
      colsum += __shfl_xor(colsum, 16);
      colsum += __shfl_xor(colsum, 32);
      if ((lane >> 4) == 0) {
        int midx = (EPI == 1) ? (col - 32) : col;
        atomicAdd(&meanbuf[(size_t)(bm >> gshift) * 128 + midx], colsum * inv_cnt);
      }
    }
  }
}

// ---------------- merged: pairnorm_c (bf16 state in xcmb) AND gather -> xugb ----------------
__global__ __launch_bounds__(256) void pnc_gather_kernel(
    const short* __restrict__ CDb, const float* __restrict__ cmean,
    short* __restrict__ xcmb,
    const float* __restrict__ Q, const int* __restrict__ cso, const int* __restrict__ cse,
    const short* __restrict__ clvl, short* __restrict__ xugb) {
  int b = blockIdx.x;
  if (b < NCLS / 4) {
    int wid = threadIdx.x >> 6;
    int lane = threadIdx.x & 63;
    int row = b * 4 + wid;
    int g = row >> 10;
    const short* xp = CDb + (size_t)row * 192 + 32;
    float y0 = bf2f(xp[lane])      - cmean[g * 128 + lane];
    float y1 = bf2f(xp[lane + 64]) - cmean[g * 128 + lane + 64];
    float ss = y0 * y0 + y1 * y1;
    #pragma unroll
    for (int o = 32; o > 0; o >>= 1) ss += __shfl_xor(ss, o);
    float inv = rsqrtf(ss * (1.f / 128.f) + 1e-6f);
    short* sp = xcmb + (size_t)row * 192;
    float s0 = y0 * inv * 0.25f + 0.1f * bf2f(sp[lane]);
    float s1 = y1 * inv * 0.25f + 0.1f * bf2f(sp[lane + 64]);
    sp[lane]      = f2bf(s0);
    sp[lane + 64] = f2bf(s1);
  } else {
    int t = (b - NCLS / 4) * 256 + threadIdx.x;
    int v = t >> 5, m = t & 31;
    float q = Q[(size_t)v * 32 + m];
    float sig = 1.f / (1.f + expf(-q));
    float vgs = 0.f, lps = 0.f, lns = 0.f;
    int e0 = cso[v], e1 = cso[v + 1];
    for (int e = e0; e < e1; ++e) {
      int ent = cse[e];
      int c = ent >> 1;
      bool pos = ent & 1;
      float clc = bf2f(clvl[(size_t)c * 64 + m]);
      float vl  = bf2f(clvl[(size_t)c * 64 + 32 + m]);
      vgs -= clc * (sig - (pos ? 0.f : 1.f));
      if (pos) lps += vl; else lns += vl;
    }
    short* xp = xugb + (size_t)v * 256 + 128;
    xp[m]      = f2bf(vgs);
    xp[32 + m] = f2bf(lps);
    xp[64 + m] = f2bf(lns);
  }
}

// ---------------- pair_norm + state update (bf16 state in xugb) ----------------
__global__ __launch_bounds__(256) void pairnorm_update_kernel(
    const short* __restrict__ CDb, const float* __restrict__ vmean,
    short* __restrict__ xugb) {
  int wid = threadIdx.x >> 6;
  int lane = threadIdx.x & 63;
  int row = blockIdx.x * 4 + wid;
  int g = row >> 9;   // 512 rows per graph
  float y0 = bf2f(CDb[(size_t)row * 128 + lane])      - vmean[g * 128 + lane];
  float y1 = bf2f(CDb[(size_t)row * 128 + lane + 64]) - vmean[g * 128 + lane + 64];
  float ss = y0 * y0 + y1 * y1;
  #pragma unroll
  for (int o = 32; o > 0; o >>= 1) ss += __shfl_xor(ss, o);
  float inv = rsqrtf(ss * (1.f / 128.f) + 1e-6f);
  short* sp = xugb + (size_t)row * 256;
  float s0 = y0 * inv * 0.25f + 0.1f * bf2f(sp[lane]);
  float s1 = y1 * inv * 0.25f + 0.1f * bf2f(sp[lane + 64]);
  sp[lane]      = f2bf(s0);
  sp[lane + 64] = f2bf(s1);
}

// ---------------- fused vo MLP: xugb[:, :128] -> logits f32 ----------------
__global__ __launch_bounds__(256) void fused_vo_kernel(
    const short* __restrict__ xugb,
    const short* __restrict__ w0, const short* __restrict__ w1,
    const float* __restrict__ b0, const float* __restrict__ b1,
    const float* __restrict__ w2, const float* __restrict__ b2,
    float* __restrict__ logits) {
  __shared__ short A[64 * 128];
  __shared__ short H1[4][16 * 128];
  __shared__ short H2[4][16 * 128];
  const int wid = threadIdx.x >> 6, lane = threadIdx.x & 63;
  const int rbase = blockIdx.x * 64 + wid * 16;
  #pragma unroll
  for (int i = 0; i < 4; ++i) {
    int s = i * 64 + lane;
    int row = s >> 4, c8 = s & 15;
    *(bf16x8*)&A[(wid * 16 + row) * 128 + c8 * 8] =
        *(const bf16x8*)&xugb[(size_t)(rbase + row) * 256 + c8 * 8];
  }
  const int kof = (lane >> 4) * 8;
  const int l15 = lane & 15;
  f32x4 acc[8] = {};
  #pragma unroll
  for (int ks = 0; ks < 4; ++ks) {
    bf16x8 a = *(const bf16x8*)&A[(wid * 16 + l15) * 128 + ks * 32 + kof];
    #pragma unroll
    for (int ni = 0; ni < 8; ++ni) {
      bf16x8 b = *(const bf16x8*)&w0[(ni * 16 + l15) * 128 + ks * 32 + kof];
      acc[ni] = __builtin_amdgcn_mfma_f32_16x16x32_bf16(a, b, acc[ni], 0, 0, 0);
    }
  }
  #pragma unroll
  for (int ni = 0; ni < 8; ++ni) {
    int col = ni * 16 + l15;
    float bb = b0[col];
    #pragma unroll
    for (int j = 0; j < 4; ++j) {
      float v = acc[ni][j] + bb; v = v > 0.f ? v : 0.2f * v;
      H1[wid][((lane >> 4) * 4 + j) * 128 + col] = f2bf(v);
    }
  }
  f32x4 acc2[8] = {};
  #pragma unroll
  for (int ks = 0; ks < 4; ++ks) {
    bf16x8 a = *(const bf16x8*)&H1[wid][l15 * 128 + ks * 32 + kof];
    #pragma unroll
    for (int ni = 0; ni < 8; ++ni) {
      bf16x8 b = *(const bf16x8*)&w1[(ni * 16 + l15) * 128 + ks * 32 + kof];
      acc2[ni] = __builtin_amdgcn_mfma_f32_16x16x32_bf16(a, b, acc2[ni], 0, 0, 0);
    }
  }
  #pragma unroll
  for (int ni = 0; ni < 8; ++ni) {
    int col = ni * 16 + l15;
    float bb = b1[col];
    #pragma unroll
    for (int j = 0; j < 4; ++j) {
      float v = acc2[ni][j] + bb; v = v > 0.f ? v : 0.2f * v;
      H2[wid][((lane >> 4) * 4 + j) * 128 + col] = f2bf(v);
    }
  }
  {
    int row = lane >> 2, q = lane & 3;
    float s = 0.f;
    #pragma unroll
    for (int jj = 0; jj < 4; ++jj) {
      bf16x8 h = *(const bf16x8*)&H2[wid][row * 128 + q * 32 + jj * 8];
      #pragma unroll
      for (int e = 0; e < 8; ++e) s += bf2f(h[e]) * w2[q * 32 + jj * 8 + e];
    }
    s += __shfl_xor(s, 1);
    s += __shfl_xor(s, 2);
    if (q == 0) logits[rbase + row] = s + b2[0];
  }
}

// ---------------- standalone loss (final round only) ----------------
__global__ __launch_bounds__(1024) void fused_loss_kernel(
    const float* __restrict__ logits, const int* __restrict__ lit_var,
    const int* __restrict__ lit_sign, float* __restrict__ loss) {
  __shared__ float lg[512];
  __shared__ float red[16];
  int g = blockIdx.x, tid = threadIdx.x;
  if (tid < 512) lg[tid] = logits[(size_t)g * 512 + tid];
  __syncthreads();
  int c = g * 1024 + tid;
  float s = 0.f;
  #pragma unroll
  for (int i = 0; i < 3; ++i) {
    int l = 3 * c + i;
    float sg = (float)lit_sign[l];
    s += softplus_f(lg[lit_var[l] - g * 512] * sg);
  }
  float vv = expf(-s);
  float pcv = vv * (-logf(1.f - vv + 1e-8f));
  #pragma unroll
  for (int o = 32; o > 0; o >>= 1) pcv += __shfl_xor(pcv, o);
  if ((tid & 63) == 0) red[tid >> 6] = pcv;
  __syncthreads();
  if (tid < 16) {
    float x = red[tid];
    #pragma unroll
    for (int o = 8; o > 0; o >>= 1) x += __shfl_xor(x, o);
    if (tid == 0) atomicAdd(loss, sqrtf(x + 1e-6f));
  }
}

__global__ void finalize_kernel(const float* __restrict__ loss_acc, float* __restrict__ out) {
  out[0] = loss_acc[0] * 0.25f;
}

// =======================================================================
extern "C" void kernel_launch(void* const* d_in, const int* in_sizes, int n_in,
                              void* d_out, int out_size, void* d_ws, size_t ws_size,
                              hipStream_t stream) {
  const int* lit_var    = (const int*)d_in[0];
  const int* lit_sign   = (const int*)d_in[1];
  const int* lit_clause = (const int*)d_in[2];
  const float* noise    = (const float*)d_in[5];
  const float* vq_w0 = (const float*)d_in[6];   const float* vq_b0 = (const float*)d_in[7];
  const float* vq_w1 = (const float*)d_in[8];   const float* vq_b1 = (const float*)d_in[9];
  const float* vq_w2 = (const float*)d_in[10];  const float* vq_b2 = (const float*)d_in[11];
  const float* cm_w0 = (const float*)d_in[12];  const float* cm_b0 = (const float*)d_in[13];
  const float* cm_w1 = (const float*)d_in[14];  const float* cm_b1 = (const float*)d_in[15];
  const float* cm_w2 = (const float*)d_in[16];  const float* cm_b2 = (const float*)d_in[17];
  const float* ug_w0 = (const float*)d_in[18];  const float* ug_b0 = (const float*)d_in[19];
  const float* ug_w1 = (const float*)d_in[20];  const float* ug_b1 = (const float*)d_in[21];
  const float* ug_w2 = (const float*)d_in[22];  const float* ug_b2 = (const float*)d_in[23];
  const float* vo_w0 = (const float*)d_in[24];  const float* vo_b0 = (const float*)d_in[25];
  const float* vo_w1 = (const float*)d_in[26];  const float* vo_b1 = (const float*)d_in[27];
  const float* vo_w2 = (const float*)d_in[28];  const float* vo_b2 = (const float*)d_in[29];

  float* ws = (float*)d_ws;
  short* clvl  = (short*)(ws + OFF_CLVL);
  short* xcmb  = (short*)(ws + OFF_XCMB);
  short* xugb  = (short*)(ws + OFF_XUGB);
  short* bufA  = (short*)(ws + OFF_ABUF);
  short* bufB  = (short*)(ws + OFF_BBUF);
  short* CDb   = (short*)(ws + OFF_CD);
  float* Q     = ws + OFF_Q;
  float* cmean = ws + OFF_CMEAN;
  float* vmean = ws + OFF_VMEAN;
  float* loss  = ws + OFF_LOSS;
  int*   cso   = (int*)(ws + OFF_CSO);
  int*   cse   = (int*)(ws + OFF_CSE);
  int*   csc   = (int*)(ws + OFF_CSC);
  short* wt    = (short*)(ws + OFF_WT);
  float* logits = (float*)d_out;
  float* loss_out = (float*)d_out + NVARS;

  convert_all_kernel<<<1984, 256, 0, stream>>>(cm_w0, cm_w1, cm_w2, ug_w0, ug_w1, ug_w2,
                                               vo_w0, vo_w1, vq_w0, vq_w1, vq_w2, wt);
  init_state_kernel<<<30784, 256, 0, stream>>>(xugb, xcmb, loss, csc);
  csr_count_kernel<<<NLITS / 256, 256, 0, stream>>>(lit_var, csc);
  csr_scan_kernel<<<1, 1024, 0, stream>>>(csc, cso, csc);
  csr_fill_kernel<<<NLITS / 256, 256, 0, stream>>>(lit_var, lit_sign, lit_clause, csc, cse);

  for (int r = 0; r < NROUNDS; ++r) {
    const float* noise_r = noise + (size_t)r * NVARS * 4;

    // vq MLP -> Q (+ absorbed loss of round r-1 for r>0)
    fused_vq_kernel<<<NVARS / 64, 256, 0, stream>>>(
        xugb, noise_r, wt + WT_VQ0, wt + WT_VQ1, wt + WT_VQ2, vq_b0, vq_b1, vq_b2, Q,
        logits, lit_var, lit_sign, loss, r > 0 ? 1 : 0);

    // clause_val -> clvl + xcmb tail; zero means
    fused_clause_kernel<<<NCLS * 32 / 256, 256, 0, stream>>>(Q, lit_var, lit_sign, xcmb, clvl, cmean);

    // cm MLP
    gemm_mfma_kernel<128, true, true, 0><<<dim3(3, NCLS / 128), 256, 0, stream>>>(
        xcmb, 192, wt + WT_CM0, cm_b0, 384, bufA, 384, 192, nullptr, nullptr, 0.f, 0);
    gemm_mfma_kernel<128, true, true, 0><<<dim3(3, NCLS / 128), 256, 0, stream>>>(
        bufA, 384, wt + WT_CM1, cm_b1, 384, bufB, 384, 384, nullptr, nullptr, 0.f, 0);
    gemm_mfma_kernel<64, false, false, 1><<<dim3(3, NCLS / 128), 256, 0, stream>>>(
        bufB, 384, wt + WT_CM2, cm_b2, 160, CDb, 192, 384, clvl, cmean, 1.f / 1024.f, 10);

    // pairnorm_c (bf16 state) + gather (vg/lp/ln -> xugb cols 128..223)
    pnc_gather_kernel<<<NCLS / 4 + NVARS * 32 / 256, 256, 0, stream>>>(
        CDb, cmean, xcmb, Q, cso, cse, clvl, xugb);

    // ug MLP
    gemm_mfma_kernel<128, true, true, 0><<<dim3(2, NVARS / 128), 256, 0, stream>>>(
        xugb, 256, wt + WT_UG0, ug_b0, 256, bufA, 256, 256, nullptr, nullptr, 0.f, 0);
    gemm_mfma_kernel<128, true, true, 0><<<dim3(2, NVARS / 128), 256, 0, stream>>>(
        bufA, 256, wt + WT_UG1, ug_b1, 256, bufB, 256, 256, nullptr, nullptr, 0.f, 0);
    gemm_mfma_kernel<64, false, false, 2><<<dim3(2, NVARS / 128), 256, 0, stream>>>(
        bufB, 256, wt + WT_UG2, ug_b2, 128, CDb, 128, 256, nullptr, vmean, 1.f / 512.f, 9);

    // variables pair_norm update (bf16 state in xugb)
    pairnorm_update_kernel<<<NVARS / 4, 256, 0, stream>>>(CDb, vmean, xugb);

    // vo MLP -> logits
    fused_vo_kernel<<<NVARS / 64, 256, 0, stream>>>(
        xugb, wt + WT_VO0, wt + WT_VO1, vo_b0, vo_b1, vo_w2, vo_b2, logits);
  }

  // final round's loss (rounds 0..2 were absorbed into vq of rounds 1..3)
  fused_loss_kernel<<<NG, 1024, 0, stream>>>(logits, lit_var, lit_sign, loss);
  finalize_kernel<<<1, 1, 0, stream>>>(loss, loss_out);
}